// Round 2
// 145.618 us; speedup vs baseline: 1.0975x; 1.0975x over previous
//
#include <hip/hip_runtime.h>

// Problem constants (match reference)
#define Tn 4
#define Bn 512
#define Gn 16
#define Nn 256               // Gn*Gn
#define Dn 32
#define NBLK ((Tn - 1) * Bn) // 1536 blocks
#define ZST 18               // uint stride/cell in f16 LDS tiles (72B, b64-aligned)

#define THRESH_C 0.5f
#define EPS_POOL 1e-6f
#define ZCMW 5.0f
#define NEGBIG -1e30f

typedef unsigned int uint_t;
typedef __attribute__((ext_vector_type(2))) unsigned short u16x2;
typedef __attribute__((ext_vector_type(2))) unsigned int   u32x2;
typedef __attribute__((ext_vector_type(4))) unsigned int   u32x4;
typedef __attribute__((ext_vector_type(8))) _Float16       f16x8;
typedef __attribute__((ext_vector_type(4))) float          f32x4;

static_assert(sizeof(f16x8) == 16, "f16x8 must be 16B");

// pack two f32 -> two f16 (RTZ; monotone on non-negatives: commutes with max)
__device__ __forceinline__ uint_t pkf16(float lo, float hi) {
    auto h = __builtin_amdgcn_cvt_pkrtz(lo, hi);   // __fp16 ext_vector_type(2)
    return __builtin_bit_cast(uint_t, h);
}
__device__ __forceinline__ float f16lo(uint_t u) {
    return (float)__builtin_bit_cast(_Float16, (unsigned short)(u & 0xFFFFu));
}
__device__ __forceinline__ float f16hi(uint_t u) {
    return (float)__builtin_bit_cast(_Float16, (unsigned short)(u >> 16));
}
// packed max of two f16 pairs; valid because all values >= 0 (f16 order == u16 order)
__device__ __forceinline__ uint_t pkmax(uint_t a, uint_t b) {
    u16x2 r = __builtin_elementwise_max(__builtin_bit_cast(u16x2, a),
                                        __builtin_bit_cast(u16x2, b));
    return __builtin_bit_cast(uint_t, r);
}

// ws: partials[5][NBLK] floats, then unsigned ctr.
// k: 0=z_what_loss 1=z_pres_loss 2=pool_loss 3=objects_loss 4=n_obj
__global__ __launch_bounds__(512, 6) void fused_losses(
    const float* __restrict__ z_what,
    const float* __restrict__ z_pres_prob,
    const float* __restrict__ z_pres,
    const float* __restrict__ base_losses,
    const int* __restrict__ gstep,
    float* __restrict__ partials,
    unsigned* __restrict__ ctr,
    float* __restrict__ out)
{
    __shared__ uint_t s_z1h[Nn * ZST];      // z1 in f16 pairs (B-frag source)    18432B
    __shared__ uint_t s_rm [Nn * ZST];      // row-max of e, f16 pairs            18432B
    __shared__ float  s_band[3 * Nn * 3];   // [di][cell][djslot] Gram band        9216B
    __shared__ float2 s_np[Nn];             // {p1, 1/max(n1,1e-5)}                2048B
    __shared__ float  s_red[8 * 5];
    __shared__ int    s_last;

    const int tid  = threadIdx.x;      // 0..511
    const int cell = tid >> 1;         // 0..255
    const int half = tid & 1;          // which 16 dims
    const int lane = tid & 63;
    const int wv   = tid >> 6;         // wave 0..7
    const int t = blockIdx.x >> 9;     // Bn = 512
    const int b = blockIdx.x & (Bn - 1);
    const int i = cell >> 4, j = cell & 15;

    const size_t cb0 = ((size_t)t * Bn + b) * Nn;
    const size_t cb1 = cb0 + (size_t)Bn * Nn;

    const float p0 = z_pres_prob[cb0 + cell];
    const float p1 = z_pres_prob[cb1 + cell];

    const float4* g0 = (const float4*)(z_what + (cb0 + cell) * Dn + half * 16);
    const float4* g1 = (const float4*)(z_what + (cb1 + cell) * Dn + half * 16);

    // ---- load own 16 dims; keep z0,z1 as packed f16, e = |z0|*p0 packed f16
    uint_t pz0[8], pz1[8], pe[8];
    float zwl_acc = 0.f, n0sq = 0.f, n1sq = 0.f;
    #pragma unroll
    for (int k = 0; k < 4; ++k) {
        float4 v0 = g0[k], v1 = g1[k];
        float c0[4] = { v0.x, v0.y, v0.z, v0.w };
        float c1[4] = { v1.x, v1.y, v1.z, v1.w };
        #pragma unroll
        for (int c = 0; c < 4; ++c) {
            float df = c1[c] - c0[c];
            zwl_acc += df * df;
            n0sq += c0[c] * c0[c];
            n1sq += c1[c] * c1[c];
        }
        pz0[2*k]   = pkf16(c0[0], c0[1]);
        pz0[2*k+1] = pkf16(c0[2], c0[3]);
        pz1[2*k]   = pkf16(c1[0], c1[1]);
        pz1[2*k+1] = pkf16(c1[2], c1[3]);
        pe[2*k]    = pkf16(fabsf(c0[0]) * p0, fabsf(c0[1]) * p0);
        pe[2*k+1]  = pkf16(fabsf(c0[2]) * p0, fabsf(c0[3]) * p0);
    }
    n0sq += __shfl_xor(n0sq, 1);       // pair-combine (xor-1 -> DPP)
    n1sq += __shfl_xor(n1sq, 1);
    const float inv_n0 = 1.0f / fmaxf(sqrtf(n0sq), 1e-5f);

    // ---- row-max of e via in-wave shuffles (rows = 32 aligned lanes; clamp edges)
    const int lL = (j > 0)  ? lane - 2 : lane;
    const int lR = (j < 15) ? lane + 2 : lane;
    uint_t rm[8];
    #pragma unroll
    for (int q = 0; q < 8; ++q) {
        uint_t e  = pe[q];
        uint_t el = __shfl(e, lL);
        uint_t er = __shfl(e, lR);
        rm[q] = pkmax(e, pkmax(el, er));
    }

    // ---- stage z1 (f16) and row-max to LDS
    {
        uint_t* zp = &s_z1h[cell * ZST + half * 8];
        uint_t* rp = &s_rm [cell * ZST + half * 8];
        #pragma unroll
        for (int q = 0; q < 4; ++q) {
            u32x2 a; a.x = pz1[2*q]; a.y = pz1[2*q+1];
            ((u32x2*)zp)[q] = a;
            u32x2 r; r.x = rm[2*q];  r.y = rm[2*q+1];
            ((u32x2*)rp)[q] = r;
        }
        if (half == 0)
            s_np[cell] = make_float2(p1, 1.0f / fmaxf(sqrtf(n1sq), 1e-5f));
    }
    __syncthreads();   // B1: z1h + rm + np visible

    // ---- col-max (clamp) + pool cosine vs |z1|*p1
    float dotp = 0.f, nasq = 0.f;
    {
        const int cu = (i > 0)  ? cell - Gn : cell;
        const int cd = (i < 15) ? cell + Gn : cell;
        const u32x2* ub = (const u32x2*)&s_rm[cu * ZST + half * 8];
        const u32x2* db = (const u32x2*)&s_rm[cd * ZST + half * 8];
        #pragma unroll
        for (int q = 0; q < 4; ++q) {
            u32x2 uu = ub[q], dd = db[q];
            #pragma unroll
            for (int c = 0; c < 2; ++c) {
                uint_t mx = pkmax(rm[2*q + c], pkmax(uu[c], dd[c]));
                float m0 = f16lo(mx), m1 = f16hi(mx);
                uint_t z = pz1[2*q + c];
                float b0 = fabsf(f16lo(z)), b1 = fabsf(f16hi(z));
                dotp += m0 * b0 + m1 * b1;    // * p1 hoisted below
                nasq += m0 * m0 + m1 * m1;
            }
        }
    }
    dotp += __shfl_xor(dotp, 1);
    nasq += __shfl_xor(nasq, 1);
    dotp *= p1;
    const float nbsq = n1sq * p1 * p1;        // exact ||(|z1|*p1)||^2
    float cosv = dotp / fmaxf(sqrtf(nasq) * sqrtf(nbsq), EPS_POOL);
    float pool_acc = (half == 0) ? (-cosv * 0.5f * (p0 + p1)) : 0.f;

    // ---- objects: banded Gram via MFMA.
    // Tile (I, di): G[m][n] = dot(z0[16I+m], z1[16J+n]), J=(I+di)&15.
    // Wave wv owns I in {2wv, 2wv+1} x di in {-1,0,1} = 6 tiles.
    const int hq = lane >> 4;          // k-chunk 0..3 (k = 8*hq..8*hq+7)
    const int mq = lane & 15;          // row (A) / col (B) within tile

    // A-frags gathered from own wave's registers:
    // cell 16I+mq is thread (2*(16*ii+mq) + hq>>1) of this wave; uints 4*(hq&1)..+3
    const int srcA = 2 * mq + (hq >> 1);
    const bool hiQ = (hq & 1) != 0;
    uint_t a0f[4], a1f[4];
    #pragma unroll
    for (int q = 0; q < 4; ++q) {
        uint_t lo0 = __shfl(pz0[q],     srcA);
        uint_t hi0 = __shfl(pz0[q + 4], srcA);
        a0f[q] = hiQ ? hi0 : lo0;
        uint_t lo1 = __shfl(pz0[q],     srcA + 32);
        uint_t hi1 = __shfl(pz0[q + 4], srcA + 32);
        a1f[q] = hiQ ? hi1 : lo1;
    }
    f16x8 Afr[2];
    {
        u32x4 ta; ta.x = a0f[0]; ta.y = a0f[1]; ta.z = a0f[2]; ta.w = a0f[3];
        Afr[0] = __builtin_bit_cast(f16x8, ta);
        u32x4 tb; tb.x = a1f[0]; tb.y = a1f[1]; tb.z = a1f[2]; tb.w = a1f[3];
        Afr[1] = __builtin_bit_cast(f16x8, tb);
    }

    // B-frags from LDS: distinct J = (2wv-1+bx)&15, bx=0..3
    f16x8 Bfr[4];
    #pragma unroll
    for (int bx = 0; bx < 4; ++bx) {
        const int J = (2 * wv - 1 + bx) & 15;
        const u32x2* bp = (const u32x2*)&s_z1h[(J * 16 + mq) * ZST + hq * 4];
        u32x2 w0 = bp[0], w1 = bp[1];
        u32x4 tb; tb.x = w0.x; tb.y = w0.y; tb.z = w1.x; tb.w = w1.y;
        Bfr[bx] = __builtin_bit_cast(f16x8, tb);
    }

    // 6 MFMAs + band extraction.
    // D layout (HW-verified): lane holds col = mq, rows = 4*hq + r.
    // Entry (row jr, col mq) needed iff (mq - jr) mod 16 in {15,0,1} -> slot {0,1,2}.
    #pragma unroll
    for (int di1 = 0; di1 < 3; ++di1) {
        #pragma unroll
        for (int ii = 0; ii < 2; ++ii) {
            const int I = 2 * wv + ii;
            f32x4 acc = { 0.f, 0.f, 0.f, 0.f };
            acc = __builtin_amdgcn_mfma_f32_16x16x32_f16(Afr[ii], Bfr[di1 + ii], acc, 0, 0, 0);
            #pragma unroll
            for (int r = 0; r < 4; ++r) {
                const int jr = 4 * hq + r;
                const int delta = (mq - jr) & 15;
                if (delta <= 1 || delta == 15) {
                    const int slot = (delta == 15) ? 0 : (delta + 1);
                    s_band[(di1 * Nn + I * 16 + jr) * 3 + slot] = acc[r];
                }
            }
        }
    }
    __syncthreads();   // B2: band visible

    // ---- objects epilogue: 9 neighbors split 5/4 across the thread pair
    float sum_sim = 0.f, max_sim = NEGBIG, anyf = 0.f;
    #pragma unroll
    for (int kk = 0; kk < 5; ++kk) {
        const int n = kk + 5 * half;       // half0: 0..4, half1: 5..9 (9 skipped)
        if (n < 9) {
            const int di = (n >= 6) ? 1 : ((n >= 3) ? 0 : -1);
            const int dj = n - (di + 1) * 3 - 1;
            const int nb = (((i + di) & 15) << 4) | ((j + dj) & 15);
            float2 np = s_np[nb];
            float g = s_band[((di + 1) * Nn + cell) * 3 + (dj + 1)];
            float s = g * inv_n0 * np.y;
            bool m = np.x > THRESH_C;
            sum_sim += m ? s : 0.f;
            max_sim = fmaxf(max_sim, m ? s : NEGBIG);
            anyf += m ? 1.f : 0.f;
        }
    }
    sum_sim += __shfl_xor(sum_sim, 1);
    anyf    += __shfl_xor(anyf, 1);
    max_sim  = fmaxf(max_sim, __shfl_xor(max_sim, 1));
    const bool det = p0 > THRESH_C;
    float obj_acc = (det && (anyf > 0.f) && half == 0) ? (sum_sim - ZCMW * max_sim) : 0.f;
    float cnt = (det && half == 0) ? 1.f : 0.f;

    // ---- z_pres_loss (t index covered by blocks with t < T-2)
    float zpl_acc = 0.f;
    if (half == 0 && t < Tn - 2) {
        const size_t zi = cb0 + cell;
        float q0 = z_pres[zi];
        float q1 = z_pres[zi + (size_t)Bn * Nn];
        float q2 = z_pres[zi + 2 * (size_t)Bn * Nn];
        float sim = 1.f - (q2 - q0) * (q2 - q0);
        zpl_acc = sim * ((q2 - q1) * (q2 - q1) + (q0 - q1) * (q0 - q1));
    }

    // ---- block reduction: wave shuffle -> LDS
    float vals[5] = { zwl_acc, zpl_acc, pool_acc, obj_acc, cnt };
    #pragma unroll
    for (int k = 0; k < 5; ++k) {
        float v = vals[k];
        #pragma unroll
        for (int off = 32; off; off >>= 1) v += __shfl_down(v, off);
        if (lane == 0) s_red[wv * 5 + k] = v;
    }
    __syncthreads();

    if (tid == 0) {
        #pragma unroll
        for (int k = 0; k < 5; ++k) {
            float v = 0.f;
            #pragma unroll
            for (int w = 0; w < 8; ++w) v += s_red[w * 5 + k];
            partials[k * NBLK + blockIdx.x] = v;
        }
        __threadfence();                    // release partials
        unsigned prev = atomicAdd(ctr, 1u); // device-scope
        s_last = (prev == NBLK - 1) ? 1 : 0;
    }
    __syncthreads();

    // ---- last block reduces all partials and finalizes (no 2nd launch)
    if (s_last) {
        __threadfence();                    // acquire
        float acc[5] = { 0.f, 0.f, 0.f, 0.f, 0.f };
        for (int idx = tid; idx < NBLK; idx += 512) {
            #pragma unroll
            for (int k = 0; k < 5; ++k) acc[k] += partials[k * NBLK + idx];
        }
        #pragma unroll
        for (int k = 0; k < 5; ++k) {
            float v = acc[k];
            #pragma unroll
            for (int off = 32; off; off >>= 1) v += __shfl_down(v, off);
            if (lane == 0) s_red[wv * 5 + k] = v;
        }
        __syncthreads();
        if (tid == 0) {
            float r[5];
            #pragma unroll
            for (int k = 0; k < 5; ++k) {
                float v = 0.f;
                #pragma unroll
                for (int w = 0; w < 8; ++w) v += s_red[w * 5 + k];
                r[k] = v;
            }
            float bl = base_losses[0] + base_losses[1] + base_losses[2] + base_losses[3];
            float scaling = fminf(1.0f, (float)gstep[0] / 300000.0f);
            out[0] = bl + r[0] * 10.0f + r[1] + r[2] + r[3] * scaling * 10.0f;
            out[1] = r[0];
            out[2] = r[1];
            out[3] = r[2];
            out[4] = r[3];
            out[5] = r[4];
        }
    }
}

extern "C" void kernel_launch(void* const* d_in, const int* in_sizes, int n_in,
                              void* d_out, int out_size, void* d_ws, size_t ws_size,
                              hipStream_t stream) {
    const float* z_what      = (const float*)d_in[0];
    const float* z_pres_prob = (const float*)d_in[1];
    const float* z_pres      = (const float*)d_in[2];
    const float* base_losses = (const float*)d_in[3];
    const int*   gstep       = (const int*)d_in[4];

    float* partials = (float*)d_ws;                       // 5*NBLK floats
    unsigned* ctr   = (unsigned*)(partials + 5 * NBLK);   // 4 bytes

    (void)hipMemsetAsync(ctr, 0, sizeof(unsigned), stream);
    fused_losses<<<dim3(NBLK), dim3(512), 0, stream>>>(
        z_what, z_pres_prob, z_pres, base_losses, gstep,
        partials, ctr, (float*)d_out);
}

// Round 3
// 129.525 us; speedup vs baseline: 1.2339x; 1.1242x over previous
//
#include <hip/hip_runtime.h>

// Problem constants (match reference)
#define Tn 4
#define Bn 512
#define Gn 16
#define Nn 256               // Gn*Gn
#define Dn 32
#define NBLK Bn              // 512 blocks, one per batch element b
#define ZST 18               // uint stride/cell in f16 LDS tiles (72B, b64-aligned)

#define THRESH_C 0.5f
#define EPS_POOL 1e-6f
#define ZCMW 5.0f
#define NEGBIG -1e30f

typedef unsigned int uint_t;
typedef __attribute__((ext_vector_type(2))) unsigned short u16x2;
typedef __attribute__((ext_vector_type(2))) unsigned int   u32x2;
typedef __attribute__((ext_vector_type(4))) unsigned int   u32x4;
typedef __attribute__((ext_vector_type(8))) _Float16       f16x8;
typedef __attribute__((ext_vector_type(2))) __fp16         hf2;
typedef __attribute__((ext_vector_type(4))) float          f32x4;

static_assert(sizeof(f16x8) == 16, "f16x8 must be 16B");

// pack two f32 -> two f16 (RTZ; monotone on non-negatives: commutes with max)
__device__ __forceinline__ uint_t pkf16(float lo, float hi) {
    auto h = __builtin_amdgcn_cvt_pkrtz(lo, hi);   // __fp16 ext_vector_type(2)
    return __builtin_bit_cast(uint_t, h);
}
__device__ __forceinline__ float f16lo(uint_t u) {
    return (float)__builtin_bit_cast(_Float16, (unsigned short)(u & 0xFFFFu));
}
__device__ __forceinline__ float f16hi(uint_t u) {
    return (float)__builtin_bit_cast(_Float16, (unsigned short)(u >> 16));
}
// packed max of two f16 pairs; valid because all values >= 0 (f16 order == u16 order)
__device__ __forceinline__ uint_t pkmax(uint_t a, uint_t b) {
    u16x2 r = __builtin_elementwise_max(__builtin_bit_cast(u16x2, a),
                                        __builtin_bit_cast(u16x2, b));
    return __builtin_bit_cast(uint_t, r);
}
// acc += a.lo*b.lo + a.hi*b.hi  (f16 inputs, f32 accumulate)
__device__ __forceinline__ float dot2acc(uint_t a, uint_t b, float acc) {
#if __has_builtin(__builtin_amdgcn_fdot2)
    return __builtin_amdgcn_fdot2(__builtin_bit_cast(hf2, a),
                                  __builtin_bit_cast(hf2, b), acc, false);
#else
    return acc + f16lo(a) * f16lo(b) + f16hi(a) * f16hi(b);
#endif
}

// ws: partials[5][NBLK] floats, then unsigned ctr.
// k: 0=z_what_loss 1=z_pres_loss 2=pool_loss 3=objects_loss 4=n_obj
__global__ __launch_bounds__(512, 4) void fused_losses(
    const float* __restrict__ z_what,
    const float* __restrict__ z_pres_prob,
    const float* __restrict__ z_pres,
    const float* __restrict__ base_losses,
    const int* __restrict__ gstep,
    float* __restrict__ partials,
    unsigned* __restrict__ ctr,
    float* __restrict__ out)
{
    __shared__ uint_t s_zt[2][Nn * ZST];    // ping-pong z-slice tiles (f16)    2x18432B
    __shared__ uint_t s_rm [Nn * ZST];      // row-max of e, f16 pairs            18432B
    __shared__ float  s_band[3 * Nn * 3];   // [di][cell][djslot] Gram band        9216B
    __shared__ float2 s_np[Nn];             // {p1, 1/max(n1,1e-5)}                2048B
    __shared__ float  s_red[8 * 5];
    __shared__ int    s_last;

    const int tid  = threadIdx.x;      // 0..511
    const int cell = tid >> 1;         // 0..255
    const int half = tid & 1;          // which 16 dims
    const int lane = tid & 63;
    const int wv   = tid >> 6;         // wave 0..7
    const int b    = blockIdx.x;       // one block per batch element
    const int i = cell >> 4, j = cell & 15;
    const int hq = lane >> 4;          // k-chunk 0..3 for MFMA frags
    const int mq = lane & 15;          // row (A) / col (B) within tile

    // ---- per-cell presence probs for all 4 timesteps
    float p4[4];
    #pragma unroll
    for (int s = 0; s < 4; ++s)
        p4[s] = z_pres_prob[((size_t)s * Bn + b) * Nn + cell];
    float q4[4] = { 0.f, 0.f, 0.f, 0.f };
    if (half == 0) {
        #pragma unroll
        for (int s = 0; s < 4; ++s)
            q4[s] = z_pres[((size_t)s * Bn + b) * Nn + cell];
    }

    const float*  zbase = z_what + (((size_t)b) * Nn + cell) * Dn + half * 16;
    const size_t  ZSL   = (size_t)Bn * Nn * Dn;   // slice stride (floats)

    // ---- slice 0: f32 kept in zf, pack e, stage f16 tile 0
    float zf[16];
    float n0sq;
    uint_t peC[8];
    {
        const float4* g = (const float4*)zbase;
        float ns = 0.f;
        uint_t* zp = &s_zt[0][cell * ZST + half * 8];
        #pragma unroll
        for (int k2 = 0; k2 < 4; ++k2) {
            float4 v = g[k2];
            float c[4] = { v.x, v.y, v.z, v.w };
            #pragma unroll
            for (int cc = 0; cc < 4; ++cc) {
                ns += c[cc] * c[cc];
                zf[4 * k2 + cc] = c[cc];
            }
            u32x2 a; a.x = pkf16(c[0], c[1]); a.y = pkf16(c[2], c[3]);
            ((u32x2*)zp)[k2] = a;
            peC[2*k2]   = pkf16(fabsf(c[0]) * p4[0], fabsf(c[1]) * p4[0]);
            peC[2*k2+1] = pkf16(fabsf(c[2]) * p4[0], fabsf(c[3]) * p4[0]);
        }
        ns += __shfl_xor(ns, 1);
        n0sq = ns;
    }
    // prefetch slice 1
    float4 pf[4];
    {
        const float4* g = (const float4*)(zbase + ZSL);
        #pragma unroll
        for (int k2 = 0; k2 < 4; ++k2) pf[k2] = g[k2];
    }

    // ---- band-extraction constants (lane-dependent, loop-invariant)
    int  boff[4];
    bool bhit[4];
    #pragma unroll
    for (int r = 0; r < 4; ++r) {
        const int jr = 4 * hq + r;
        const int delta = (mq - jr) & 15;
        bhit[r] = (delta <= 1) || (delta == 15);
        const int slot = (delta == 15) ? 0 : (delta + 1);
        boff[r] = jr * 3 + slot;
    }

    float zwl_acc = 0.f, zpl_acc = 0.f, pool_acc = 0.f, obj_acc = 0.f, cnt = 0.f;

    #pragma unroll
    for (int t = 0; t < 3; ++t) {
        // ---- consume prefetched slice t+1; issue loads for slice t+2
        float4 ww[4] = { pf[0], pf[1], pf[2], pf[3] };
        if (t < 2) {
            const float4* g = (const float4*)(zbase + (size_t)(t + 2) * ZSL);
            #pragma unroll
            for (int k2 = 0; k2 < 4; ++k2) pf[k2] = g[k2];
        }
        const float p0 = p4[t], p1 = p4[t + 1];

        uint_t pzN[8], peN[8];
        float n1 = 0.f, zw = 0.f;
        #pragma unroll
        for (int k2 = 0; k2 < 4; ++k2) {
            float c[4] = { ww[k2].x, ww[k2].y, ww[k2].z, ww[k2].w };
            #pragma unroll
            for (int cc = 0; cc < 4; ++cc) {
                float d = c[cc] - zf[4 * k2 + cc];
                zw += d * d;
                n1 += c[cc] * c[cc];
                zf[4 * k2 + cc] = c[cc];
            }
            pzN[2*k2]   = pkf16(c[0], c[1]);
            pzN[2*k2+1] = pkf16(c[2], c[3]);
            peN[2*k2]   = pkf16(fabsf(c[0]) * p1, fabsf(c[1]) * p1);
            peN[2*k2+1] = pkf16(fabsf(c[2]) * p1, fabsf(c[3]) * p1);
        }
        zwl_acc += zw;
        n1 += __shfl_xor(n1, 1);
        const float n1sq = n1;
        const float inv_n0 = 1.0f / fmaxf(sqrtf(n0sq), 1e-5f);

        // ---- row-max of e (slice t) via in-wave shuffles (clamped edges)
        const int lL = (j > 0)  ? lane - 2 : lane;
        const int lR = (j < 15) ? lane + 2 : lane;
        uint_t rm[8];
        #pragma unroll
        for (int q = 0; q < 8; ++q) {
            uint_t e = peC[q];
            rm[q] = pkmax(e, pkmax(__shfl(e, lL), __shfl(e, lR)));
        }

        // ---- stage slice t+1 tile, row-max, np
        {
            uint_t* zp = &s_zt[(t + 1) & 1][cell * ZST + half * 8];
            uint_t* rp = &s_rm[cell * ZST + half * 8];
            #pragma unroll
            for (int q = 0; q < 4; ++q) {
                u32x2 a; a.x = pzN[2*q]; a.y = pzN[2*q+1];
                ((u32x2*)zp)[q] = a;
                u32x2 rr; rr.x = rm[2*q]; rr.y = rm[2*q+1];
                ((u32x2*)rp)[q] = rr;
            }
            if (half == 0)
                s_np[cell] = make_float2(p1, 1.0f / fmaxf(sqrtf(n1sq), 1e-5f));
        }
        __syncthreads();   // B1: tiles + rm + np visible

        // ---- pool: col-max (clamped) + cosine vs |z1|*p1 (packed f16 dot)
        float dotp = 0.f, nasq = 0.f;
        {
            const int cu = (i > 0)  ? cell - Gn : cell;
            const int cd = (i < 15) ? cell + Gn : cell;
            const u32x2* ub = (const u32x2*)&s_rm[cu * ZST + half * 8];
            const u32x2* db = (const u32x2*)&s_rm[cd * ZST + half * 8];
            #pragma unroll
            for (int q = 0; q < 4; ++q) {
                u32x2 uu = ub[q], dd = db[q];
                #pragma unroll
                for (int c2 = 0; c2 < 2; ++c2) {
                    uint_t mx = pkmax(rm[2*q + c2], pkmax(uu[c2], dd[c2]));
                    uint_t za = pzN[2*q + c2] & 0x7FFF7FFFu;
                    dotp = dot2acc(mx, za, dotp);
                    nasq = dot2acc(mx, mx, nasq);
                }
            }
        }
        dotp += __shfl_xor(dotp, 1);
        nasq += __shfl_xor(nasq, 1);
        dotp *= p1;
        const float nbsq = n1sq * p1 * p1;    // exact ||(|z1|*p1)||^2
        float cosv = dotp / fmaxf(sqrtf(nasq) * sqrtf(nbsq), EPS_POOL);
        if (half == 0) pool_acc += -cosv * 0.5f * (p0 + p1);

        // ---- banded Gram via MFMA: A = slice t tile, B = slice t+1 tile
        const uint_t* tA = &s_zt[t & 1][0];
        const uint_t* tB = &s_zt[(t + 1) & 1][0];
        f16x8 Afr[2];
        #pragma unroll
        for (int ii = 0; ii < 2; ++ii) {
            const int I = 2 * wv + ii;
            const u32x2* ap = (const u32x2*)&tA[(I * 16 + mq) * ZST + hq * 4];
            u32x2 a0 = ap[0], a1 = ap[1];
            u32x4 ta; ta.x = a0.x; ta.y = a0.y; ta.z = a1.x; ta.w = a1.y;
            Afr[ii] = __builtin_bit_cast(f16x8, ta);
        }
        f16x8 Bfr[4];
        #pragma unroll
        for (int bx = 0; bx < 4; ++bx) {
            const int J = (2 * wv - 1 + bx) & 15;
            const u32x2* bp = (const u32x2*)&tB[(J * 16 + mq) * ZST + hq * 4];
            u32x2 b0 = bp[0], b1 = bp[1];
            u32x4 tb; tb.x = b0.x; tb.y = b0.y; tb.z = b1.x; tb.w = b1.y;
            Bfr[bx] = __builtin_bit_cast(f16x8, tb);
        }
        #pragma unroll
        for (int di1 = 0; di1 < 3; ++di1) {
            #pragma unroll
            for (int ii = 0; ii < 2; ++ii) {
                const int I = 2 * wv + ii;
                f32x4 acc = { 0.f, 0.f, 0.f, 0.f };
                acc = __builtin_amdgcn_mfma_f32_16x16x32_f16(Afr[ii], Bfr[di1 + ii], acc, 0, 0, 0);
                const int base = (di1 * Nn + I * 16) * 3;
                #pragma unroll
                for (int r = 0; r < 4; ++r)
                    if (bhit[r]) s_band[base + boff[r]] = acc[r];
            }
        }
        __syncthreads();   // B2: band visible

        // ---- objects epilogue: 9 neighbors split 5/4 across the thread pair
        {
            float sum_sim = 0.f, max_sim = NEGBIG, anyf = 0.f;
            #pragma unroll
            for (int kk = 0; kk < 5; ++kk) {
                const int n = kk + 5 * half;   // half0: 0..4, half1: 5..9 (9 skipped)
                if (n < 9) {
                    const int di = (n >= 6) ? 1 : ((n >= 3) ? 0 : -1);
                    const int dj = n - (di + 1) * 3 - 1;
                    const int nb = (((i + di) & 15) << 4) | ((j + dj) & 15);
                    float2 np = s_np[nb];
                    float g = s_band[((di + 1) * Nn + cell) * 3 + (dj + 1)];
                    float s = g * inv_n0 * np.y;
                    bool m = np.x > THRESH_C;
                    sum_sim += m ? s : 0.f;
                    max_sim = fmaxf(max_sim, m ? s : NEGBIG);
                    anyf += m ? 1.f : 0.f;
                }
            }
            sum_sim += __shfl_xor(sum_sim, 1);
            anyf    += __shfl_xor(anyf, 1);
            max_sim  = fmaxf(max_sim, __shfl_xor(max_sim, 1));
            const bool det = p0 > THRESH_C;
            if (det && half == 0) {
                cnt += 1.f;
                if (anyf > 0.f) obj_acc += sum_sim - ZCMW * max_sim;
            }
        }

        // ---- z_pres_loss term for this transition (t < T-2)
        if (half == 0 && t < 2) {
            const float qa = q4[t], qb = q4[t + 1], qc = q4[t + 2];
            const float sim = 1.f - (qc - qa) * (qc - qa);
            zpl_acc += sim * ((qc - qb) * (qc - qb) + (qa - qb) * (qa - qb));
        }

        if (t < 2) __syncthreads();   // B3: protect LDS reuse next iteration

        // ---- roll state
        n0sq = n1sq;
        #pragma unroll
        for (int q = 0; q < 8; ++q) peC[q] = peN[q];
    }

    // ---- block reduction: wave shuffle -> LDS
    float vals[5] = { zwl_acc, zpl_acc, pool_acc, obj_acc, cnt };
    #pragma unroll
    for (int k = 0; k < 5; ++k) {
        float v = vals[k];
        #pragma unroll
        for (int off = 32; off; off >>= 1) v += __shfl_down(v, off);
        if (lane == 0) s_red[wv * 5 + k] = v;
    }
    __syncthreads();

    if (tid == 0) {
        #pragma unroll
        for (int k = 0; k < 5; ++k) {
            float v = 0.f;
            #pragma unroll
            for (int w = 0; w < 8; ++w) v += s_red[w * 5 + k];
            partials[k * NBLK + blockIdx.x] = v;
        }
        __threadfence();                    // release partials
        unsigned prev = atomicAdd(ctr, 1u); // device-scope
        s_last = (prev == NBLK - 1) ? 1 : 0;
    }
    __syncthreads();

    // ---- last block reduces all partials and finalizes (no 2nd launch)
    if (s_last) {
        __threadfence();                    // acquire
        float acc[5] = { 0.f, 0.f, 0.f, 0.f, 0.f };
        for (int idx = tid; idx < NBLK; idx += 512) {
            #pragma unroll
            for (int k = 0; k < 5; ++k) acc[k] += partials[k * NBLK + idx];
        }
        #pragma unroll
        for (int k = 0; k < 5; ++k) {
            float v = acc[k];
            #pragma unroll
            for (int off = 32; off; off >>= 1) v += __shfl_down(v, off);
            if (lane == 0) s_red[wv * 5 + k] = v;
        }
        __syncthreads();
        if (tid == 0) {
            float r[5];
            #pragma unroll
            for (int k = 0; k < 5; ++k) {
                float v = 0.f;
                #pragma unroll
                for (int w = 0; w < 8; ++w) v += s_red[w * 5 + k];
                r[k] = v;
            }
            float bl = base_losses[0] + base_losses[1] + base_losses[2] + base_losses[3];
            float scaling = fminf(1.0f, (float)gstep[0] / 300000.0f);
            out[0] = bl + r[0] * 10.0f + r[1] + r[2] + r[3] * scaling * 10.0f;
            out[1] = r[0];
            out[2] = r[1];
            out[3] = r[2];
            out[4] = r[3];
            out[5] = r[4];
        }
    }
}

extern "C" void kernel_launch(void* const* d_in, const int* in_sizes, int n_in,
                              void* d_out, int out_size, void* d_ws, size_t ws_size,
                              hipStream_t stream) {
    const float* z_what      = (const float*)d_in[0];
    const float* z_pres_prob = (const float*)d_in[1];
    const float* z_pres      = (const float*)d_in[2];
    const float* base_losses = (const float*)d_in[3];
    const int*   gstep       = (const int*)d_in[4];

    float* partials = (float*)d_ws;                       // 5*NBLK floats
    unsigned* ctr   = (unsigned*)(partials + 5 * NBLK);   // 4 bytes

    (void)hipMemsetAsync(ctr, 0, sizeof(unsigned), stream);
    fused_losses<<<dim3(NBLK), dim3(512), 0, stream>>>(
        z_what, z_pres_prob, z_pres, base_losses, gstep,
        partials, ctr, (float*)d_out);
}

// Round 4
// 128.194 us; speedup vs baseline: 1.2467x; 1.0104x over previous
//
#include <hip/hip_runtime.h>

// Problem constants (match reference)
#define Tn 4
#define Bn 512
#define Gn 16
#define Nn 256               // Gn*Gn
#define Dn 32
#define NBLK Bn              // 512 blocks, one per batch element b
#define ZST 18               // uint stride/cell in f16 LDS tiles (72B, b64-aligned)

#define THRESH_C 0.5f
#define EPS_POOL 1e-6f
#define ZCMW 5.0f
#define NEGBIG -1e30f

typedef unsigned int uint_t;
typedef __attribute__((ext_vector_type(2))) unsigned short u16x2;
typedef __attribute__((ext_vector_type(2))) unsigned int   u32x2;
typedef __attribute__((ext_vector_type(4))) unsigned int   u32x4;
typedef __attribute__((ext_vector_type(8))) _Float16       f16x8;
typedef __attribute__((ext_vector_type(2))) __fp16         hf2;
typedef __attribute__((ext_vector_type(4))) float          f32x4;

static_assert(sizeof(f16x8) == 16, "f16x8 must be 16B");

// pack two f32 -> two f16 (RTZ; monotone on non-negatives: commutes with max)
__device__ __forceinline__ uint_t pkf16(float lo, float hi) {
    auto h = __builtin_amdgcn_cvt_pkrtz(lo, hi);   // __fp16 ext_vector_type(2)
    return __builtin_bit_cast(uint_t, h);
}
__device__ __forceinline__ float f16lo(uint_t u) {
    return (float)__builtin_bit_cast(_Float16, (unsigned short)(u & 0xFFFFu));
}
__device__ __forceinline__ float f16hi(uint_t u) {
    return (float)__builtin_bit_cast(_Float16, (unsigned short)(u >> 16));
}
// packed max of two f16 pairs; valid because all values >= 0 (f16 order == u16 order)
__device__ __forceinline__ uint_t pkmax(uint_t a, uint_t b) {
    u16x2 r = __builtin_elementwise_max(__builtin_bit_cast(u16x2, a),
                                        __builtin_bit_cast(u16x2, b));
    return __builtin_bit_cast(uint_t, r);
}
// acc += a.lo*b.lo + a.hi*b.hi  (f16 inputs, f32 accumulate)
__device__ __forceinline__ float dot2acc(uint_t a, uint_t b, float acc) {
#if __has_builtin(__builtin_amdgcn_fdot2)
    return __builtin_amdgcn_fdot2(__builtin_bit_cast(hf2, a),
                                  __builtin_bit_cast(hf2, b), acc, false);
#else
    return acc + f16lo(a) * f16lo(b) + f16hi(a) * f16hi(b);
#endif
}

// ws: partials[5][NBLK] floats, then unsigned ctr.
// k: 0=z_what_loss 1=z_pres_loss 2=pool_loss 3=objects_loss 4=n_obj
// launch_bounds arg2=2: empirically arg2 acts as min-BLOCKS/CU on this toolchain
// (R3: arg2=4 -> 64-VGPR cap -> 12 MB scratch spill). 2 blocks/CU = 16 waves/CU
// -> 128-VGPR cap; LDS (67 KB) limits to 2 blocks/CU anyway.
__global__ __launch_bounds__(512, 2) void fused_losses(
    const float* __restrict__ z_what,
    const float* __restrict__ z_pres_prob,
    const float* __restrict__ z_pres,
    const float* __restrict__ base_losses,
    const int* __restrict__ gstep,
    float* __restrict__ partials,
    unsigned* __restrict__ ctr,
    float* __restrict__ out)
{
    __shared__ uint_t s_zt[2][Nn * ZST];    // ping-pong z-slice tiles (f16)    2x18432B
    __shared__ uint_t s_rm [Nn * ZST];      // row-max of e, f16 pairs            18432B
    __shared__ float  s_band[3 * Nn * 3];   // [di][cell][djslot] Gram band        9216B
    __shared__ float2 s_np[Nn];             // {p1, 1/max(n1,1e-5)}                2048B
    __shared__ float  s_red[8 * 5];
    __shared__ int    s_last;

    const int tid  = threadIdx.x;      // 0..511
    const int cell = tid >> 1;         // 0..255
    const int half = tid & 1;          // which 16 dims
    const int lane = tid & 63;
    const int wv   = tid >> 6;         // wave 0..7
    const int b    = blockIdx.x;       // one block per batch element
    const int i = cell >> 4, j = cell & 15;
    const int hq = lane >> 4;          // k-chunk 0..3 for MFMA frags
    const int mq = lane & 15;          // row (A) / col (B) within tile

    // ---- per-cell presence probs for all 4 timesteps
    float p4[4];
    #pragma unroll
    for (int s = 0; s < 4; ++s)
        p4[s] = z_pres_prob[((size_t)s * Bn + b) * Nn + cell];
    float q4[4] = { 0.f, 0.f, 0.f, 0.f };
    if (half == 0) {
        #pragma unroll
        for (int s = 0; s < 4; ++s)
            q4[s] = z_pres[((size_t)s * Bn + b) * Nn + cell];
    }

    const float*  zbase = z_what + (((size_t)b) * Nn + cell) * Dn + half * 16;
    const size_t  ZSL   = (size_t)Bn * Nn * Dn;   // slice stride (floats)

    // ---- slice 0: f32 kept in zf, pack e, stage f16 tile 0
    float zf[16];
    float n0sq;
    uint_t peC[8];
    {
        const float4* g = (const float4*)zbase;
        float ns = 0.f;
        uint_t* zp = &s_zt[0][cell * ZST + half * 8];
        #pragma unroll
        for (int k2 = 0; k2 < 4; ++k2) {
            float4 v = g[k2];
            float c[4] = { v.x, v.y, v.z, v.w };
            #pragma unroll
            for (int cc = 0; cc < 4; ++cc) {
                ns += c[cc] * c[cc];
                zf[4 * k2 + cc] = c[cc];
            }
            u32x2 a; a.x = pkf16(c[0], c[1]); a.y = pkf16(c[2], c[3]);
            ((u32x2*)zp)[k2] = a;
            peC[2*k2]   = pkf16(fabsf(c[0]) * p4[0], fabsf(c[1]) * p4[0]);
            peC[2*k2+1] = pkf16(fabsf(c[2]) * p4[0], fabsf(c[3]) * p4[0]);
        }
        ns += __shfl_xor(ns, 1);
        n0sq = ns;
    }
    // prefetch slice 1
    float4 pf[4];
    {
        const float4* g = (const float4*)(zbase + ZSL);
        #pragma unroll
        for (int k2 = 0; k2 < 4; ++k2) pf[k2] = g[k2];
    }

    // ---- band-extraction constants (lane-dependent, loop-invariant)
    int  boff[4];
    bool bhit[4];
    #pragma unroll
    for (int r = 0; r < 4; ++r) {
        const int jr = 4 * hq + r;
        const int delta = (mq - jr) & 15;
        bhit[r] = (delta <= 1) || (delta == 15);
        const int slot = (delta == 15) ? 0 : (delta + 1);
        boff[r] = jr * 3 + slot;
    }

    float zwl_acc = 0.f, zpl_acc = 0.f, pool_acc = 0.f, obj_acc = 0.f, cnt = 0.f;

    #pragma unroll
    for (int t = 0; t < 3; ++t) {
        // ---- consume prefetched slice t+1; issue loads for slice t+2
        float4 ww[4] = { pf[0], pf[1], pf[2], pf[3] };
        if (t < 2) {
            const float4* g = (const float4*)(zbase + (size_t)(t + 2) * ZSL);
            #pragma unroll
            for (int k2 = 0; k2 < 4; ++k2) pf[k2] = g[k2];
        }
        const float p0 = p4[t], p1 = p4[t + 1];

        uint_t pzN[8], peN[8];
        float n1 = 0.f, zw = 0.f;
        #pragma unroll
        for (int k2 = 0; k2 < 4; ++k2) {
            float c[4] = { ww[k2].x, ww[k2].y, ww[k2].z, ww[k2].w };
            #pragma unroll
            for (int cc = 0; cc < 4; ++cc) {
                float d = c[cc] - zf[4 * k2 + cc];
                zw += d * d;
                n1 += c[cc] * c[cc];
                zf[4 * k2 + cc] = c[cc];
            }
            pzN[2*k2]   = pkf16(c[0], c[1]);
            pzN[2*k2+1] = pkf16(c[2], c[3]);
            peN[2*k2]   = pkf16(fabsf(c[0]) * p1, fabsf(c[1]) * p1);
            peN[2*k2+1] = pkf16(fabsf(c[2]) * p1, fabsf(c[3]) * p1);
        }
        zwl_acc += zw;
        n1 += __shfl_xor(n1, 1);
        const float n1sq = n1;
        const float inv_n0 = 1.0f / fmaxf(sqrtf(n0sq), 1e-5f);

        // ---- row-max of e (slice t) via in-wave shuffles (clamped edges)
        const int lL = (j > 0)  ? lane - 2 : lane;
        const int lR = (j < 15) ? lane + 2 : lane;
        uint_t rm[8];
        #pragma unroll
        for (int q = 0; q < 8; ++q) {
            uint_t e = peC[q];
            rm[q] = pkmax(e, pkmax(__shfl(e, lL), __shfl(e, lR)));
        }

        // ---- stage slice t+1 tile, row-max, np
        {
            uint_t* zp = &s_zt[(t + 1) & 1][cell * ZST + half * 8];
            uint_t* rp = &s_rm[cell * ZST + half * 8];
            #pragma unroll
            for (int q = 0; q < 4; ++q) {
                u32x2 a; a.x = pzN[2*q]; a.y = pzN[2*q+1];
                ((u32x2*)zp)[q] = a;
                u32x2 rr; rr.x = rm[2*q]; rr.y = rm[2*q+1];
                ((u32x2*)rp)[q] = rr;
            }
            if (half == 0)
                s_np[cell] = make_float2(p1, 1.0f / fmaxf(sqrtf(n1sq), 1e-5f));
        }
        __syncthreads();   // B1: tiles + rm + np visible

        // ---- pool: col-max (clamped) + cosine vs |z1|*p1 (packed f16 dot)
        float dotp = 0.f, nasq = 0.f;
        {
            const int cu = (i > 0)  ? cell - Gn : cell;
            const int cd = (i < 15) ? cell + Gn : cell;
            const u32x2* ub = (const u32x2*)&s_rm[cu * ZST + half * 8];
            const u32x2* db = (const u32x2*)&s_rm[cd * ZST + half * 8];
            #pragma unroll
            for (int q = 0; q < 4; ++q) {
                u32x2 uu = ub[q], dd = db[q];
                #pragma unroll
                for (int c2 = 0; c2 < 2; ++c2) {
                    uint_t mx = pkmax(rm[2*q + c2], pkmax(uu[c2], dd[c2]));
                    uint_t za = pzN[2*q + c2] & 0x7FFF7FFFu;
                    dotp = dot2acc(mx, za, dotp);
                    nasq = dot2acc(mx, mx, nasq);
                }
            }
        }
        dotp += __shfl_xor(dotp, 1);
        nasq += __shfl_xor(nasq, 1);
        dotp *= p1;
        const float nbsq = n1sq * p1 * p1;    // exact ||(|z1|*p1)||^2
        float cosv = dotp / fmaxf(sqrtf(nasq) * sqrtf(nbsq), EPS_POOL);
        if (half == 0) pool_acc += -cosv * 0.5f * (p0 + p1);

        // ---- banded Gram via MFMA: A = slice t tile, B = slice t+1 tile
        const uint_t* tA = &s_zt[t & 1][0];
        const uint_t* tB = &s_zt[(t + 1) & 1][0];
        f16x8 Afr[2];
        #pragma unroll
        for (int ii = 0; ii < 2; ++ii) {
            const int I = 2 * wv + ii;
            const u32x2* ap = (const u32x2*)&tA[(I * 16 + mq) * ZST + hq * 4];
            u32x2 a0 = ap[0], a1 = ap[1];
            u32x4 ta; ta.x = a0.x; ta.y = a0.y; ta.z = a1.x; ta.w = a1.y;
            Afr[ii] = __builtin_bit_cast(f16x8, ta);
        }
        f16x8 Bfr[4];
        #pragma unroll
        for (int bx = 0; bx < 4; ++bx) {
            const int J = (2 * wv - 1 + bx) & 15;
            const u32x2* bp = (const u32x2*)&tB[(J * 16 + mq) * ZST + hq * 4];
            u32x2 b0 = bp[0], b1 = bp[1];
            u32x4 tb; tb.x = b0.x; tb.y = b0.y; tb.z = b1.x; tb.w = b1.y;
            Bfr[bx] = __builtin_bit_cast(f16x8, tb);
        }
        #pragma unroll
        for (int di1 = 0; di1 < 3; ++di1) {
            #pragma unroll
            for (int ii = 0; ii < 2; ++ii) {
                const int I = 2 * wv + ii;
                f32x4 acc = { 0.f, 0.f, 0.f, 0.f };
                acc = __builtin_amdgcn_mfma_f32_16x16x32_f16(Afr[ii], Bfr[di1 + ii], acc, 0, 0, 0);
                const int base = (di1 * Nn + I * 16) * 3;
                #pragma unroll
                for (int r = 0; r < 4; ++r)
                    if (bhit[r]) s_band[base + boff[r]] = acc[r];
            }
        }
        __syncthreads();   // B2: band visible

        // ---- objects epilogue: 9 neighbors split 5/4 across the thread pair
        {
            float sum_sim = 0.f, max_sim = NEGBIG, anyf = 0.f;
            #pragma unroll
            for (int kk = 0; kk < 5; ++kk) {
                const int n = kk + 5 * half;   // half0: 0..4, half1: 5..9 (9 skipped)
                if (n < 9) {
                    const int di = (n >= 6) ? 1 : ((n >= 3) ? 0 : -1);
                    const int dj = n - (di + 1) * 3 - 1;
                    const int nb = (((i + di) & 15) << 4) | ((j + dj) & 15);
                    float2 np = s_np[nb];
                    float g = s_band[((di + 1) * Nn + cell) * 3 + (dj + 1)];
                    float s = g * inv_n0 * np.y;
                    bool m = np.x > THRESH_C;
                    sum_sim += m ? s : 0.f;
                    max_sim = fmaxf(max_sim, m ? s : NEGBIG);
                    anyf += m ? 1.f : 0.f;
                }
            }
            sum_sim += __shfl_xor(sum_sim, 1);
            anyf    += __shfl_xor(anyf, 1);
            max_sim  = fmaxf(max_sim, __shfl_xor(max_sim, 1));
            const bool det = p0 > THRESH_C;
            if (det && half == 0) {
                cnt += 1.f;
                if (anyf > 0.f) obj_acc += sum_sim - ZCMW * max_sim;
            }
        }

        // ---- z_pres_loss term for this transition (t < T-2)
        if (half == 0 && t < 2) {
            const float qa = q4[t], qb = q4[t + 1], qc = q4[t + 2];
            const float sim = 1.f - (qc - qa) * (qc - qa);
            zpl_acc += sim * ((qc - qb) * (qc - qb) + (qa - qb) * (qa - qb));
        }

        if (t < 2) __syncthreads();   // B3: protect LDS reuse next iteration

        // ---- roll state
        n0sq = n1sq;
        #pragma unroll
        for (int q = 0; q < 8; ++q) peC[q] = peN[q];
    }

    // ---- block reduction: wave shuffle -> LDS
    float vals[5] = { zwl_acc, zpl_acc, pool_acc, obj_acc, cnt };
    #pragma unroll
    for (int k = 0; k < 5; ++k) {
        float v = vals[k];
        #pragma unroll
        for (int off = 32; off; off >>= 1) v += __shfl_down(v, off);
        if (lane == 0) s_red[wv * 5 + k] = v;
    }
    __syncthreads();

    if (tid == 0) {
        #pragma unroll
        for (int k = 0; k < 5; ++k) {
            float v = 0.f;
            #pragma unroll
            for (int w = 0; w < 8; ++w) v += s_red[w * 5 + k];
            partials[k * NBLK + blockIdx.x] = v;
        }
        __threadfence();                    // release partials
        unsigned prev = atomicAdd(ctr, 1u); // device-scope
        s_last = (prev == NBLK - 1) ? 1 : 0;
    }
    __syncthreads();

    // ---- last block reduces all partials and finalizes (no 2nd launch)
    if (s_last) {
        __threadfence();                    // acquire
        float acc[5] = { 0.f, 0.f, 0.f, 0.f, 0.f };
        for (int idx = tid; idx < NBLK; idx += 512) {
            #pragma unroll
            for (int k = 0; k < 5; ++k) acc[k] += partials[k * NBLK + idx];
        }
        #pragma unroll
        for (int k = 0; k < 5; ++k) {
            float v = acc[k];
            #pragma unroll
            for (int off = 32; off; off >>= 1) v += __shfl_down(v, off);
            if (lane == 0) s_red[wv * 5 + k] = v;
        }
        __syncthreads();
        if (tid == 0) {
            float r[5];
            #pragma unroll
            for (int k = 0; k < 5; ++k) {
                float v = 0.f;
                #pragma unroll
                for (int w = 0; w < 8; ++w) v += s_red[w * 5 + k];
                r[k] = v;
            }
            float bl = base_losses[0] + base_losses[1] + base_losses[2] + base_losses[3];
            float scaling = fminf(1.0f, (float)gstep[0] / 300000.0f);
            out[0] = bl + r[0] * 10.0f + r[1] + r[2] + r[3] * scaling * 10.0f;
            out[1] = r[0];
            out[2] = r[1];
            out[3] = r[2];
            out[4] = r[3];
            out[5] = r[4];
        }
    }
}

extern "C" void kernel_launch(void* const* d_in, const int* in_sizes, int n_in,
                              void* d_out, int out_size, void* d_ws, size_t ws_size,
                              hipStream_t stream) {
    const float* z_what      = (const float*)d_in[0];
    const float* z_pres_prob = (const float*)d_in[1];
    const float* z_pres      = (const float*)d_in[2];
    const float* base_losses = (const float*)d_in[3];
    const int*   gstep       = (const int*)d_in[4];

    float* partials = (float*)d_ws;                       // 5*NBLK floats
    unsigned* ctr   = (unsigned*)(partials + 5 * NBLK);   // 4 bytes

    (void)hipMemsetAsync(ctr, 0, sizeof(unsigned), stream);
    fused_losses<<<dim3(NBLK), dim3(512), 0, stream>>>(
        z_what, z_pres_prob, z_pres, base_losses, gstep,
        partials, ctr, (float*)d_out);
}

// Round 5
// 117.281 us; speedup vs baseline: 1.3627x; 1.0931x over previous
//
#include <hip/hip_runtime.h>

// Problem constants (match reference)
#define Tn 4
#define Bn 512
#define Gn 16
#define Nn 256               // Gn*Gn
#define Dn 32
#define NBLK Bn              // 512 blocks, one per batch element b
#define ZST 18               // uint stride/cell in f16 LDS tiles (72B, b64-aligned)

#define THRESH_C 0.5f
#define EPS_POOL 1e-6f
#define ZCMW 5.0f
#define NEGBIG -1e30f

typedef unsigned int uint_t;
typedef __attribute__((ext_vector_type(2))) unsigned short u16x2;
typedef __attribute__((ext_vector_type(2))) unsigned int   u32x2;
typedef __attribute__((ext_vector_type(4))) unsigned int   u32x4;
typedef __attribute__((ext_vector_type(8))) _Float16       f16x8;
typedef __attribute__((ext_vector_type(2))) __fp16         hf2;
typedef __attribute__((ext_vector_type(4))) float          f32x4;

static_assert(sizeof(f16x8) == 16, "f16x8 must be 16B");

// pack two f32 -> two f16 (RTZ; monotone on non-negatives: commutes with max)
__device__ __forceinline__ uint_t pkf16(float lo, float hi) {
    auto h = __builtin_amdgcn_cvt_pkrtz(lo, hi);   // __fp16 ext_vector_type(2)
    return __builtin_bit_cast(uint_t, h);
}
__device__ __forceinline__ float f16lo(uint_t u) {
    return (float)__builtin_bit_cast(_Float16, (unsigned short)(u & 0xFFFFu));
}
__device__ __forceinline__ float f16hi(uint_t u) {
    return (float)__builtin_bit_cast(_Float16, (unsigned short)(u >> 16));
}
// packed max of two f16 pairs; valid because all values >= 0 (f16 order == u16 order)
__device__ __forceinline__ uint_t pkmax(uint_t a, uint_t b) {
    u16x2 r = __builtin_elementwise_max(__builtin_bit_cast(u16x2, a),
                                        __builtin_bit_cast(u16x2, b));
    return __builtin_bit_cast(uint_t, r);
}
// acc += a.lo*b.lo + a.hi*b.hi  (f16 inputs, f32 accumulate)
__device__ __forceinline__ float dot2acc(uint_t a, uint_t b, float acc) {
#if __has_builtin(__builtin_amdgcn_fdot2)
    return __builtin_amdgcn_fdot2(__builtin_bit_cast(hf2, a),
                                  __builtin_bit_cast(hf2, b), acc, false);
#else
    return acc + f16lo(a) * f16lo(b) + f16hi(a) * f16hi(b);
#endif
}

// ws: partials[5][NBLK] floats.
// k: 0=z_what_loss 1=z_pres_loss 2=pool_loss 3=objects_loss 4=n_obj
// launch_bounds arg2=2: empirically arg2 acts as min-BLOCKS/CU on this toolchain
// (R3: arg2=4 -> 64-VGPR cap -> 12 MB scratch spill). 2 blocks/CU = 16 waves/CU
// -> 128-VGPR cap; LDS (67 KB) limits to 2 blocks/CU anyway.
__global__ __launch_bounds__(512, 2) void fused_losses(
    const float* __restrict__ z_what,
    const float* __restrict__ z_pres_prob,
    const float* __restrict__ z_pres,
    float* __restrict__ partials)
{
    __shared__ uint_t s_zt[2][Nn * ZST];    // ping-pong z-slice tiles (f16)    2x18432B
    __shared__ uint_t s_rm [Nn * ZST];      // row-max of e, f16 pairs            18432B
    __shared__ float  s_band[3 * Nn * 3];   // [di][cell][djslot] Gram band        9216B
    __shared__ float2 s_np[Nn];             // {p1, 1/max(n1,1e-5)}                2048B
    __shared__ float  s_red[8 * 5];

    const int tid  = threadIdx.x;      // 0..511
    const int cell = tid >> 1;         // 0..255
    const int half = tid & 1;          // which 16 dims
    const int lane = tid & 63;
    const int wv   = tid >> 6;         // wave 0..7
    const int b    = blockIdx.x;       // one block per batch element
    const int i = cell >> 4, j = cell & 15;
    const int hq = lane >> 4;          // k-chunk 0..3 for MFMA frags
    const int mq = lane & 15;          // row (A) / col (B) within tile

    // ---- per-cell presence probs for all 4 timesteps
    float p4[4];
    #pragma unroll
    for (int s = 0; s < 4; ++s)
        p4[s] = z_pres_prob[((size_t)s * Bn + b) * Nn + cell];
    float q4[4] = { 0.f, 0.f, 0.f, 0.f };
    if (half == 0) {
        #pragma unroll
        for (int s = 0; s < 4; ++s)
            q4[s] = z_pres[((size_t)s * Bn + b) * Nn + cell];
    }

    const float*  zbase = z_what + (((size_t)b) * Nn + cell) * Dn + half * 16;
    const size_t  ZSL   = (size_t)Bn * Nn * Dn;   // slice stride (floats)

    // ---- slice 0: f32 kept in zf, pack e, stage f16 tile 0
    float zf[16];
    float n0sq;
    uint_t peC[8];
    {
        const float4* g = (const float4*)zbase;
        float ns = 0.f;
        uint_t* zp = &s_zt[0][cell * ZST + half * 8];
        #pragma unroll
        for (int k2 = 0; k2 < 4; ++k2) {
            float4 v = g[k2];
            float c[4] = { v.x, v.y, v.z, v.w };
            #pragma unroll
            for (int cc = 0; cc < 4; ++cc) {
                ns += c[cc] * c[cc];
                zf[4 * k2 + cc] = c[cc];
            }
            u32x2 a; a.x = pkf16(c[0], c[1]); a.y = pkf16(c[2], c[3]);
            ((u32x2*)zp)[k2] = a;
            peC[2*k2]   = pkf16(fabsf(c[0]) * p4[0], fabsf(c[1]) * p4[0]);
            peC[2*k2+1] = pkf16(fabsf(c[2]) * p4[0], fabsf(c[3]) * p4[0]);
        }
        ns += __shfl_xor(ns, 1);
        n0sq = ns;
    }
    // prefetch slice 1
    float4 pf[4];
    {
        const float4* g = (const float4*)(zbase + ZSL);
        #pragma unroll
        for (int k2 = 0; k2 < 4; ++k2) pf[k2] = g[k2];
    }

    // ---- band-extraction constants (lane-dependent, loop-invariant)
    int  boff[4];
    bool bhit[4];
    #pragma unroll
    for (int r = 0; r < 4; ++r) {
        const int jr = 4 * hq + r;
        const int delta = (mq - jr) & 15;
        bhit[r] = (delta <= 1) || (delta == 15);
        const int slot = (delta == 15) ? 0 : (delta + 1);
        boff[r] = jr * 3 + slot;
    }

    float zwl_acc = 0.f, zpl_acc = 0.f, pool_acc = 0.f, obj_acc = 0.f, cnt = 0.f;

    #pragma unroll
    for (int t = 0; t < 3; ++t) {
        // ---- consume prefetched slice t+1; issue loads for slice t+2
        float4 ww[4] = { pf[0], pf[1], pf[2], pf[3] };
        if (t < 2) {
            const float4* g = (const float4*)(zbase + (size_t)(t + 2) * ZSL);
            #pragma unroll
            for (int k2 = 0; k2 < 4; ++k2) pf[k2] = g[k2];
        }
        const float p0 = p4[t], p1 = p4[t + 1];

        uint_t pzN[8], peN[8];
        float n1 = 0.f, zw = 0.f;
        #pragma unroll
        for (int k2 = 0; k2 < 4; ++k2) {
            float c[4] = { ww[k2].x, ww[k2].y, ww[k2].z, ww[k2].w };
            #pragma unroll
            for (int cc = 0; cc < 4; ++cc) {
                float d = c[cc] - zf[4 * k2 + cc];
                zw += d * d;
                n1 += c[cc] * c[cc];
                zf[4 * k2 + cc] = c[cc];
            }
            pzN[2*k2]   = pkf16(c[0], c[1]);
            pzN[2*k2+1] = pkf16(c[2], c[3]);
            peN[2*k2]   = pkf16(fabsf(c[0]) * p1, fabsf(c[1]) * p1);
            peN[2*k2+1] = pkf16(fabsf(c[2]) * p1, fabsf(c[3]) * p1);
        }
        zwl_acc += zw;
        n1 += __shfl_xor(n1, 1);
        const float n1sq = n1;
        const float inv_n0 = 1.0f / fmaxf(sqrtf(n0sq), 1e-5f);

        // ---- row-max of e (slice t) via in-wave shuffles (clamped edges)
        const int lL = (j > 0)  ? lane - 2 : lane;
        const int lR = (j < 15) ? lane + 2 : lane;
        uint_t rm[8];
        #pragma unroll
        for (int q = 0; q < 8; ++q) {
            uint_t e = peC[q];
            rm[q] = pkmax(e, pkmax(__shfl(e, lL), __shfl(e, lR)));
        }

        // ---- stage slice t+1 tile, row-max, np
        {
            uint_t* zp = &s_zt[(t + 1) & 1][cell * ZST + half * 8];
            uint_t* rp = &s_rm[cell * ZST + half * 8];
            #pragma unroll
            for (int q = 0; q < 4; ++q) {
                u32x2 a; a.x = pzN[2*q]; a.y = pzN[2*q+1];
                ((u32x2*)zp)[q] = a;
                u32x2 rr; rr.x = rm[2*q]; rr.y = rm[2*q+1];
                ((u32x2*)rp)[q] = rr;
            }
            if (half == 0)
                s_np[cell] = make_float2(p1, 1.0f / fmaxf(sqrtf(n1sq), 1e-5f));
        }
        __syncthreads();   // B1: tiles + rm + np visible

        // ---- pool: col-max (clamped) + cosine vs |z1|*p1 (packed f16 dot)
        float dotp = 0.f, nasq = 0.f;
        {
            const int cu = (i > 0)  ? cell - Gn : cell;
            const int cd = (i < 15) ? cell + Gn : cell;
            const u32x2* ub = (const u32x2*)&s_rm[cu * ZST + half * 8];
            const u32x2* db = (const u32x2*)&s_rm[cd * ZST + half * 8];
            #pragma unroll
            for (int q = 0; q < 4; ++q) {
                u32x2 uu = ub[q], dd = db[q];
                #pragma unroll
                for (int c2 = 0; c2 < 2; ++c2) {
                    uint_t mx = pkmax(rm[2*q + c2], pkmax(uu[c2], dd[c2]));
                    uint_t za = pzN[2*q + c2] & 0x7FFF7FFFu;
                    dotp = dot2acc(mx, za, dotp);
                    nasq = dot2acc(mx, mx, nasq);
                }
            }
        }
        dotp += __shfl_xor(dotp, 1);
        nasq += __shfl_xor(nasq, 1);
        dotp *= p1;
        const float nbsq = n1sq * p1 * p1;    // exact ||(|z1|*p1)||^2
        float cosv = dotp / fmaxf(sqrtf(nasq) * sqrtf(nbsq), EPS_POOL);
        if (half == 0) pool_acc += -cosv * 0.5f * (p0 + p1);

        // ---- banded Gram via MFMA: A = slice t tile, B = slice t+1 tile
        const uint_t* tA = &s_zt[t & 1][0];
        const uint_t* tB = &s_zt[(t + 1) & 1][0];
        f16x8 Afr[2];
        #pragma unroll
        for (int ii = 0; ii < 2; ++ii) {
            const int I = 2 * wv + ii;
            const u32x2* ap = (const u32x2*)&tA[(I * 16 + mq) * ZST + hq * 4];
            u32x2 a0 = ap[0], a1 = ap[1];
            u32x4 ta; ta.x = a0.x; ta.y = a0.y; ta.z = a1.x; ta.w = a1.y;
            Afr[ii] = __builtin_bit_cast(f16x8, ta);
        }
        f16x8 Bfr[4];
        #pragma unroll
        for (int bx = 0; bx < 4; ++bx) {
            const int J = (2 * wv - 1 + bx) & 15;
            const u32x2* bp = (const u32x2*)&tB[(J * 16 + mq) * ZST + hq * 4];
            u32x2 b0 = bp[0], b1 = bp[1];
            u32x4 tb; tb.x = b0.x; tb.y = b0.y; tb.z = b1.x; tb.w = b1.y;
            Bfr[bx] = __builtin_bit_cast(f16x8, tb);
        }
        #pragma unroll
        for (int di1 = 0; di1 < 3; ++di1) {
            #pragma unroll
            for (int ii = 0; ii < 2; ++ii) {
                const int I = 2 * wv + ii;
                f32x4 acc = { 0.f, 0.f, 0.f, 0.f };
                acc = __builtin_amdgcn_mfma_f32_16x16x32_f16(Afr[ii], Bfr[di1 + ii], acc, 0, 0, 0);
                const int base = (di1 * Nn + I * 16) * 3;
                #pragma unroll
                for (int r = 0; r < 4; ++r)
                    if (bhit[r]) s_band[base + boff[r]] = acc[r];
            }
        }
        __syncthreads();   // B2: band visible

        // ---- objects epilogue: 9 neighbors split 5/4 across the thread pair
        {
            float sum_sim = 0.f, max_sim = NEGBIG, anyf = 0.f;
            #pragma unroll
            for (int kk = 0; kk < 5; ++kk) {
                const int n = kk + 5 * half;   // half0: 0..4, half1: 5..9 (9 skipped)
                if (n < 9) {
                    const int di = (n >= 6) ? 1 : ((n >= 3) ? 0 : -1);
                    const int dj = n - (di + 1) * 3 - 1;
                    const int nb = (((i + di) & 15) << 4) | ((j + dj) & 15);
                    float2 np = s_np[nb];
                    float g = s_band[((di + 1) * Nn + cell) * 3 + (dj + 1)];
                    float s = g * inv_n0 * np.y;
                    bool m = np.x > THRESH_C;
                    sum_sim += m ? s : 0.f;
                    max_sim = fmaxf(max_sim, m ? s : NEGBIG);
                    anyf += m ? 1.f : 0.f;
                }
            }
            sum_sim += __shfl_xor(sum_sim, 1);
            anyf    += __shfl_xor(anyf, 1);
            max_sim  = fmaxf(max_sim, __shfl_xor(max_sim, 1));
            const bool det = p0 > THRESH_C;
            if (det && half == 0) {
                cnt += 1.f;
                if (anyf > 0.f) obj_acc += sum_sim - ZCMW * max_sim;
            }
        }

        // ---- z_pres_loss term for this transition (t < T-2)
        if (half == 0 && t < 2) {
            const float qa = q4[t], qb = q4[t + 1], qc = q4[t + 2];
            const float sim = 1.f - (qc - qa) * (qc - qa);
            zpl_acc += sim * ((qc - qb) * (qc - qb) + (qa - qb) * (qa - qb));
        }

        if (t < 2) __syncthreads();   // B3: protect LDS reuse next iteration

        // ---- roll state
        n0sq = n1sq;
        #pragma unroll
        for (int q = 0; q < 8; ++q) peC[q] = peN[q];
    }

    // ---- block reduction: wave shuffle -> LDS -> partials write. No atomics,
    // no fences, no single-kernel fan-in tail (R4: that tail was ~30 us of the
    // 45 us dispatch). finalize kernel (same stream) does the global reduce.
    float vals[5] = { zwl_acc, zpl_acc, pool_acc, obj_acc, cnt };
    #pragma unroll
    for (int k = 0; k < 5; ++k) {
        float v = vals[k];
        #pragma unroll
        for (int off = 32; off; off >>= 1) v += __shfl_down(v, off);
        if (lane == 0) s_red[wv * 5 + k] = v;
    }
    __syncthreads();

    if (tid == 0) {
        #pragma unroll
        for (int k = 0; k < 5; ++k) {
            float v = 0.f;
            #pragma unroll
            for (int w = 0; w < 8; ++w) v += s_red[w * 5 + k];
            partials[k * NBLK + blockIdx.x] = v;
        }
    }
}

// 1 block, 512 threads (= NBLK): deterministic final reduction + output.
__global__ __launch_bounds__(512, 1) void finalize(
    const float* __restrict__ partials,
    const float* __restrict__ base_losses,
    const int* __restrict__ gstep,
    float* __restrict__ out)
{
    __shared__ float s_red[8 * 5];
    const int tid  = threadIdx.x;
    const int lane = tid & 63;
    const int wv   = tid >> 6;

    float acc[5];
    #pragma unroll
    for (int k = 0; k < 5; ++k) acc[k] = partials[k * NBLK + tid];

    #pragma unroll
    for (int k = 0; k < 5; ++k) {
        float v = acc[k];
        #pragma unroll
        for (int off = 32; off; off >>= 1) v += __shfl_down(v, off);
        if (lane == 0) s_red[wv * 5 + k] = v;
    }
    __syncthreads();

    if (tid == 0) {
        float r[5];
        #pragma unroll
        for (int k = 0; k < 5; ++k) {
            float v = 0.f;
            #pragma unroll
            for (int w = 0; w < 8; ++w) v += s_red[w * 5 + k];
            r[k] = v;
        }
        float bl = base_losses[0] + base_losses[1] + base_losses[2] + base_losses[3];
        float scaling = fminf(1.0f, (float)gstep[0] / 300000.0f);
        out[0] = bl + r[0] * 10.0f + r[1] + r[2] + r[3] * scaling * 10.0f;
        out[1] = r[0];
        out[2] = r[1];
        out[3] = r[2];
        out[4] = r[3];
        out[5] = r[4];
    }
}

extern "C" void kernel_launch(void* const* d_in, const int* in_sizes, int n_in,
                              void* d_out, int out_size, void* d_ws, size_t ws_size,
                              hipStream_t stream) {
    const float* z_what      = (const float*)d_in[0];
    const float* z_pres_prob = (const float*)d_in[1];
    const float* z_pres      = (const float*)d_in[2];
    const float* base_losses = (const float*)d_in[3];
    const int*   gstep       = (const int*)d_in[4];

    float* partials = (float*)d_ws;   // 5*NBLK floats

    fused_losses<<<dim3(NBLK), dim3(512), 0, stream>>>(
        z_what, z_pres_prob, z_pres, partials);
    finalize<<<dim3(1), dim3(512), 0, stream>>>(
        partials, base_losses, gstep, (float*)d_out);
}

// Round 7
// 116.946 us; speedup vs baseline: 1.3666x; 1.0029x over previous
//
#include <hip/hip_runtime.h>

// Problem constants (match reference)
#define Tn 4
#define Bn 512
#define Gn 16
#define Nn 256               // Gn*Gn
#define Dn 32
#define NBLK Bn              // 512 blocks, one per batch element b
#define ZST 18               // uint stride/cell in f16 tiles (72B, b64-aligned)

#define THRESH_C 0.5f
#define EPS_POOL 1e-6f
#define ZCMW 5.0f
#define NEGBIG -1e30f

typedef unsigned int uint_t;
typedef __attribute__((ext_vector_type(2))) unsigned short u16x2;
typedef __attribute__((ext_vector_type(2))) unsigned int   u32x2;
typedef __attribute__((ext_vector_type(4))) unsigned int   u32x4;
typedef __attribute__((ext_vector_type(8))) _Float16       f16x8;
typedef __attribute__((ext_vector_type(2))) __fp16         hf2;
typedef __attribute__((ext_vector_type(4))) float          f32x4;

static_assert(sizeof(f16x8) == 16, "f16x8 must be 16B");

// pack two f32 -> two f16 (RTZ; monotone on non-negatives: commutes with max)
__device__ __forceinline__ uint_t pkf16(float lo, float hi) {
    auto h = __builtin_amdgcn_cvt_pkrtz(lo, hi);   // __fp16 ext_vector_type(2)
    return __builtin_bit_cast(uint_t, h);
}
__device__ __forceinline__ float f16lo(uint_t u) {
    return (float)__builtin_bit_cast(_Float16, (unsigned short)(u & 0xFFFFu));
}
__device__ __forceinline__ float f16hi(uint_t u) {
    return (float)__builtin_bit_cast(_Float16, (unsigned short)(u >> 16));
}
// packed max of two f16 pairs; valid because all values >= 0 (f16 order == u16 order)
__device__ __forceinline__ uint_t pkmax(uint_t a, uint_t b) {
    u16x2 r = __builtin_elementwise_max(__builtin_bit_cast(u16x2, a),
                                        __builtin_bit_cast(u16x2, b));
    return __builtin_bit_cast(uint_t, r);
}
// acc += a.lo*b.lo + a.hi*b.hi  (f16 inputs, f32 accumulate)
__device__ __forceinline__ float dot2acc(uint_t a, uint_t b, float acc) {
#if __has_builtin(__builtin_amdgcn_fdot2)
    return __builtin_amdgcn_fdot2(__builtin_bit_cast(hf2, a),
                                  __builtin_bit_cast(hf2, b), acc, false);
#else
    return acc + f16lo(a) * f16lo(b) + f16hi(a) * f16hi(b);
#endif
}

// ws: partials[5][NBLK] floats.
// k: 0=z_what_loss 1=z_pres_loss 2=pool_loss 3=objects_loss 4=n_obj
// launch_bounds arg2=2: empirically arg2 acts as min-BLOCKS/CU on this toolchain
// (R3: arg2=4 -> 64-VGPR cap -> 12 MB scratch spill). Compiler floor only;
// at ~76 VGPR + 47 KB LDS the runtime can fit 3 blocks/CU.
// R6 lesson: s_rm needs 16 uints/cell (D=32 dims) — the RST=10 compaction read
// past the stride (NaN from uninit LDS). Keep the R4-proven stride-18 layout.
__global__ __launch_bounds__(512, 2) void fused_losses(
    const float* __restrict__ z_what,
    const float* __restrict__ z_pres_prob,
    const float* __restrict__ z_pres,
    float* __restrict__ partials)
{
    __shared__ uint_t s_z [Nn * ZST];       // single z-slice tile (f16)          18432B
    __shared__ uint_t s_rm[Nn * ZST];       // row-max of e, f16 pairs            18432B
    __shared__ float  s_band[3 * Nn * 3];   // [di][cell][djslot] Gram band        9216B
    __shared__ float2 s_np[Nn];             // {p1, 1/max(n1,1e-5)}                2048B
    __shared__ float  s_red[8 * 5];

    const int tid  = threadIdx.x;      // 0..511
    const int cell = tid >> 1;         // 0..255
    const int half = tid & 1;          // which 16 dims
    const int lane = tid & 63;
    const int wv   = tid >> 6;         // wave 0..7
    const int b    = blockIdx.x;       // one block per batch element
    const int i = cell >> 4, j = cell & 15;
    const int hq = lane >> 4;          // k-chunk 0..3 for MFMA frags
    const int mq = lane & 15;          // row (A) / col (B) within tile

    // ---- per-cell presence probs for all 4 timesteps
    float p4[4];
    #pragma unroll
    for (int s = 0; s < 4; ++s)
        p4[s] = z_pres_prob[((size_t)s * Bn + b) * Nn + cell];
    float q4[4] = { 0.f, 0.f, 0.f, 0.f };
    if (half == 0) {
        #pragma unroll
        for (int s = 0; s < 4; ++s)
            q4[s] = z_pres[((size_t)s * Bn + b) * Nn + cell];
    }

    const float*  zbase = z_what + (((size_t)b) * Nn + cell) * Dn + half * 16;
    const size_t  ZSL   = (size_t)Bn * Nn * Dn;   // slice stride (floats)

    // ---- slice 0: f32 kept in zf, pack e, stage f16 tile 0 (Afr bootstrap)
    float zf[16];
    float n0sq;
    uint_t peC[8];
    {
        const float4* g = (const float4*)zbase;
        float ns = 0.f;
        uint_t* zp = &s_z[cell * ZST + half * 8];
        #pragma unroll
        for (int k2 = 0; k2 < 4; ++k2) {
            float4 v = g[k2];
            float c[4] = { v.x, v.y, v.z, v.w };
            #pragma unroll
            for (int cc = 0; cc < 4; ++cc) {
                ns += c[cc] * c[cc];
                zf[4 * k2 + cc] = c[cc];
            }
            u32x2 a; a.x = pkf16(c[0], c[1]); a.y = pkf16(c[2], c[3]);
            ((u32x2*)zp)[k2] = a;
            peC[2*k2]   = pkf16(fabsf(c[0]) * p4[0], fabsf(c[1]) * p4[0]);
            peC[2*k2+1] = pkf16(fabsf(c[2]) * p4[0], fabsf(c[3]) * p4[0]);
        }
        ns += __shfl_xor(ns, 1);
        n0sq = ns;
    }
    // prefetch slice 1
    float4 pf[4];
    {
        const float4* g = (const float4*)(zbase + ZSL);
        #pragma unroll
        for (int k2 = 0; k2 < 4; ++k2) pf[k2] = g[k2];
    }
    __syncthreads();   // P1: tile 0 visible

    // ---- bootstrap A-frags (rows I=2wv, 2wv+1 of slice 0); carried in regs after
    f16x8 Afr[2];
    #pragma unroll
    for (int ii = 0; ii < 2; ++ii) {
        const int I = 2 * wv + ii;
        const u32x2* ap = (const u32x2*)&s_z[(I * 16 + mq) * ZST + hq * 4];
        u32x2 a0 = ap[0], a1 = ap[1];
        u32x4 ta; ta.x = a0.x; ta.y = a0.y; ta.z = a1.x; ta.w = a1.y;
        Afr[ii] = __builtin_bit_cast(f16x8, ta);
    }
    __syncthreads();   // P2: Afr reads done before tile 1 overwrites s_z

    // ---- band-extraction constants (lane-dependent, loop-invariant)
    int  boff[4];
    bool bhit[4];
    #pragma unroll
    for (int r = 0; r < 4; ++r) {
        const int jr = 4 * hq + r;
        const int delta = (mq - jr) & 15;
        bhit[r] = (delta <= 1) || (delta == 15);
        const int slot = (delta == 15) ? 0 : (delta + 1);
        boff[r] = jr * 3 + slot;
    }

    float zwl_acc = 0.f, zpl_acc = 0.f, pool_acc = 0.f, obj_acc = 0.f, cnt = 0.f;

    #pragma unroll
    for (int t = 0; t < 3; ++t) {
        // ---- consume prefetched slice t+1; issue loads for slice t+2
        float4 ww[4] = { pf[0], pf[1], pf[2], pf[3] };
        if (t < 2) {
            const float4* g = (const float4*)(zbase + (size_t)(t + 2) * ZSL);
            #pragma unroll
            for (int k2 = 0; k2 < 4; ++k2) pf[k2] = g[k2];
        }
        const float p0 = p4[t], p1 = p4[t + 1];

        uint_t pzN[8], peN[8];
        float n1 = 0.f, zw = 0.f;
        #pragma unroll
        for (int k2 = 0; k2 < 4; ++k2) {
            float c[4] = { ww[k2].x, ww[k2].y, ww[k2].z, ww[k2].w };
            #pragma unroll
            for (int cc = 0; cc < 4; ++cc) {
                float d = c[cc] - zf[4 * k2 + cc];
                zw += d * d;
                n1 += c[cc] * c[cc];
                zf[4 * k2 + cc] = c[cc];
            }
            pzN[2*k2]   = pkf16(c[0], c[1]);
            pzN[2*k2+1] = pkf16(c[2], c[3]);
            peN[2*k2]   = pkf16(fabsf(c[0]) * p1, fabsf(c[1]) * p1);
            peN[2*k2+1] = pkf16(fabsf(c[2]) * p1, fabsf(c[3]) * p1);
        }
        zwl_acc += zw;
        n1 += __shfl_xor(n1, 1);
        const float n1sq = n1;
        const float inv_n0 = 1.0f / fmaxf(sqrtf(n0sq), 1e-5f);

        // ---- row-max of e (slice t) via in-wave shuffles (clamped edges)
        const int lL = (j > 0)  ? lane - 2 : lane;
        const int lR = (j < 15) ? lane + 2 : lane;
        uint_t rm[8];
        #pragma unroll
        for (int q = 0; q < 8; ++q) {
            uint_t e = peC[q];
            rm[q] = pkmax(e, pkmax(__shfl(e, lL), __shfl(e, lR)));
        }

        // ---- stage slice t+1 tile (over slice t), row-max, np
        {
            uint_t* zp = &s_z [cell * ZST + half * 8];
            uint_t* rp = &s_rm[cell * ZST + half * 8];
            #pragma unroll
            for (int q = 0; q < 4; ++q) {
                u32x2 a; a.x = pzN[2*q]; a.y = pzN[2*q+1];
                ((u32x2*)zp)[q] = a;
                u32x2 rr; rr.x = rm[2*q]; rr.y = rm[2*q+1];
                ((u32x2*)rp)[q] = rr;
            }
            if (half == 0)
                s_np[cell] = make_float2(p1, 1.0f / fmaxf(sqrtf(n1sq), 1e-5f));
        }
        __syncthreads();   // B1: tile + rm + np visible

        // ---- pool: col-max (clamped) + cosine vs |z1|*p1 (packed f16 dot)
        float dotp = 0.f, nasq = 0.f;
        {
            const int cu = (i > 0)  ? cell - Gn : cell;
            const int cd = (i < 15) ? cell + Gn : cell;
            const u32x2* ub = (const u32x2*)&s_rm[cu * ZST + half * 8];
            const u32x2* db = (const u32x2*)&s_rm[cd * ZST + half * 8];
            #pragma unroll
            for (int q = 0; q < 4; ++q) {
                u32x2 uu = ub[q], dd = db[q];
                #pragma unroll
                for (int c2 = 0; c2 < 2; ++c2) {
                    uint_t mx = pkmax(rm[2*q + c2], pkmax(uu[c2], dd[c2]));
                    uint_t za = pzN[2*q + c2] & 0x7FFF7FFFu;
                    dotp = dot2acc(mx, za, dotp);
                    nasq = dot2acc(mx, mx, nasq);
                }
            }
        }
        dotp += __shfl_xor(dotp, 1);
        nasq += __shfl_xor(nasq, 1);
        dotp *= p1;
        const float nbsq = n1sq * p1 * p1;    // exact ||(|z1|*p1)||^2
        float cosv = dotp / fmaxf(sqrtf(nasq) * sqrtf(nbsq), EPS_POOL);
        if (half == 0) pool_acc += -cosv * 0.5f * (p0 + p1);

        // ---- banded Gram via MFMA: A = slice t (regs, carried), B = slice t+1 (LDS)
        f16x8 Bfr[4];
        #pragma unroll
        for (int bx = 0; bx < 4; ++bx) {
            const int J = (2 * wv - 1 + bx) & 15;
            const u32x2* bp = (const u32x2*)&s_z[(J * 16 + mq) * ZST + hq * 4];
            u32x2 b0 = bp[0], b1 = bp[1];
            u32x4 tb; tb.x = b0.x; tb.y = b0.y; tb.z = b1.x; tb.w = b1.y;
            Bfr[bx] = __builtin_bit_cast(f16x8, tb);
        }
        #pragma unroll
        for (int di1 = 0; di1 < 3; ++di1) {
            #pragma unroll
            for (int ii = 0; ii < 2; ++ii) {
                const int I = 2 * wv + ii;
                f32x4 acc = { 0.f, 0.f, 0.f, 0.f };
                acc = __builtin_amdgcn_mfma_f32_16x16x32_f16(Afr[ii], Bfr[di1 + ii], acc, 0, 0, 0);
                const int base = (di1 * Nn + I * 16) * 3;
                #pragma unroll
                for (int r = 0; r < 4; ++r)
                    if (bhit[r]) s_band[base + boff[r]] = acc[r];
            }
        }
        // carry: this tile's J=2wv,2wv+1 frags are next iteration's A-frags
        Afr[0] = Bfr[1];
        Afr[1] = Bfr[2];
        __syncthreads();   // B2: band visible

        // ---- objects epilogue: 9 neighbors split 5/4 across the thread pair
        {
            float sum_sim = 0.f, max_sim = NEGBIG, anyf = 0.f;
            #pragma unroll
            for (int kk = 0; kk < 5; ++kk) {
                const int n = kk + 5 * half;   // half0: 0..4, half1: 5..9 (9 skipped)
                if (n < 9) {
                    const int di = (n >= 6) ? 1 : ((n >= 3) ? 0 : -1);
                    const int dj = n - (di + 1) * 3 - 1;
                    const int nb = (((i + di) & 15) << 4) | ((j + dj) & 15);
                    float2 np = s_np[nb];
                    float g = s_band[((di + 1) * Nn + cell) * 3 + (dj + 1)];
                    float s = g * inv_n0 * np.y;
                    bool m = np.x > THRESH_C;
                    sum_sim += m ? s : 0.f;
                    max_sim = fmaxf(max_sim, m ? s : NEGBIG);
                    anyf += m ? 1.f : 0.f;
                }
            }
            sum_sim += __shfl_xor(sum_sim, 1);
            anyf    += __shfl_xor(anyf, 1);
            max_sim  = fmaxf(max_sim, __shfl_xor(max_sim, 1));
            const bool det = p0 > THRESH_C;
            if (det && half == 0) {
                cnt += 1.f;
                if (anyf > 0.f) obj_acc += sum_sim - ZCMW * max_sim;
            }
        }

        // ---- z_pres_loss term for this transition (t < T-2)
        if (half == 0 && t < 2) {
            const float qa = q4[t], qb = q4[t + 1], qc = q4[t + 2];
            const float sim = 1.f - (qc - qa) * (qc - qa);
            zpl_acc += sim * ((qc - qb) * (qc - qb) + (qa - qb) * (qa - qb));
        }

        if (t < 2) __syncthreads();   // B3: epilogue/np reads done before next stage

        // ---- roll state
        n0sq = n1sq;
        #pragma unroll
        for (int q = 0; q < 8; ++q) peC[q] = peN[q];
    }

    // ---- block reduction: wave shuffle -> LDS -> partials write. No atomics,
    // no fences, no single-kernel fan-in tail (R4: tail was ~30 us of 45 us).
    float vals[5] = { zwl_acc, zpl_acc, pool_acc, obj_acc, cnt };
    #pragma unroll
    for (int k = 0; k < 5; ++k) {
        float v = vals[k];
        #pragma unroll
        for (int off = 32; off; off >>= 1) v += __shfl_down(v, off);
        if (lane == 0) s_red[wv * 5 + k] = v;
    }
    __syncthreads();

    if (tid == 0) {
        #pragma unroll
        for (int k = 0; k < 5; ++k) {
            float v = 0.f;
            #pragma unroll
            for (int w = 0; w < 8; ++w) v += s_red[w * 5 + k];
            partials[k * NBLK + blockIdx.x] = v;
        }
    }
}

// 1 block, 512 threads (= NBLK): deterministic final reduction + output.
__global__ __launch_bounds__(512, 1) void finalize(
    const float* __restrict__ partials,
    const float* __restrict__ base_losses,
    const int* __restrict__ gstep,
    float* __restrict__ out)
{
    __shared__ float s_red[8 * 5];
    const int tid  = threadIdx.x;
    const int lane = tid & 63;
    const int wv   = tid >> 6;

    float acc[5];
    #pragma unroll
    for (int k = 0; k < 5; ++k) acc[k] = partials[k * NBLK + tid];

    #pragma unroll
    for (int k = 0; k < 5; ++k) {
        float v = acc[k];
        #pragma unroll
        for (int off = 32; off; off >>= 1) v += __shfl_down(v, off);
        if (lane == 0) s_red[wv * 5 + k] = v;
    }
    __syncthreads();

    if (tid == 0) {
        float r[5];
        #pragma unroll
        for (int k = 0; k < 5; ++k) {
            float v = 0.f;
            #pragma unroll
            for (int w = 0; w < 8; ++w) v += s_red[w * 5 + k];
            r[k] = v;
        }
        float bl = base_losses[0] + base_losses[1] + base_losses[2] + base_losses[3];
        float scaling = fminf(1.0f, (float)gstep[0] / 300000.0f);
        out[0] = bl + r[0] * 10.0f + r[1] + r[2] + r[3] * scaling * 10.0f;
        out[1] = r[0];
        out[2] = r[1];
        out[3] = r[2];
        out[4] = r[3];
        out[5] = r[4];
    }
}

extern "C" void kernel_launch(void* const* d_in, const int* in_sizes, int n_in,
                              void* d_out, int out_size, void* d_ws, size_t ws_size,
                              hipStream_t stream) {
    const float* z_what      = (const float*)d_in[0];
    const float* z_pres_prob = (const float*)d_in[1];
    const float* z_pres      = (const float*)d_in[2];
    const float* base_losses = (const float*)d_in[3];
    const int*   gstep       = (const int*)d_in[4];

    float* partials = (float*)d_ws;   // 5*NBLK floats

    fused_losses<<<dim3(NBLK), dim3(512), 0, stream>>>(
        z_what, z_pres_prob, z_pres, partials);
    finalize<<<dim3(1), dim3(512), 0, stream>>>(
        partials, base_losses, gstep, (float*)d_out);
}

// Round 8
// 114.725 us; speedup vs baseline: 1.3931x; 1.0194x over previous
//
#include <hip/hip_runtime.h>

// Problem constants (match reference)
#define Tn 4
#define Bn 512
#define Gn 16
#define Nn 256               // Gn*Gn
#define Dn 32
#define NBLK Bn              // 512 blocks, one per batch element b
#define ZST 18               // uint stride/cell in f16 tiles (72B, b64-aligned)

#define THRESH_C 0.5f
#define EPS_POOL 1e-6f
#define ZCMW 5.0f
#define NEGBIG -1e30f

typedef unsigned int uint_t;
typedef __attribute__((ext_vector_type(2))) unsigned short u16x2;
typedef __attribute__((ext_vector_type(2))) unsigned int   u32x2;
typedef __attribute__((ext_vector_type(4))) unsigned int   u32x4;
typedef __attribute__((ext_vector_type(8))) _Float16       f16x8;
typedef __attribute__((ext_vector_type(2))) __fp16         hf2;
typedef __attribute__((ext_vector_type(4))) float          f32x4;

static_assert(sizeof(f16x8) == 16, "f16x8 must be 16B");

// pack two f32 -> two f16 (RTZ; monotone on non-negatives: commutes with max)
__device__ __forceinline__ uint_t pkf16(float lo, float hi) {
    auto h = __builtin_amdgcn_cvt_pkrtz(lo, hi);   // __fp16 ext_vector_type(2)
    return __builtin_bit_cast(uint_t, h);
}
__device__ __forceinline__ float f16lo(uint_t u) {
    return (float)__builtin_bit_cast(_Float16, (unsigned short)(u & 0xFFFFu));
}
__device__ __forceinline__ float f16hi(uint_t u) {
    return (float)__builtin_bit_cast(_Float16, (unsigned short)(u >> 16));
}
// packed max of two f16 pairs; valid because all values >= 0 (f16 order == u16 order)
__device__ __forceinline__ uint_t pkmax(uint_t a, uint_t b) {
    u16x2 r = __builtin_elementwise_max(__builtin_bit_cast(u16x2, a),
                                        __builtin_bit_cast(u16x2, b));
    return __builtin_bit_cast(uint_t, r);
}
// acc += a.lo*b.lo + a.hi*b.hi  (f16 inputs, f32 accumulate)
__device__ __forceinline__ float dot2acc(uint_t a, uint_t b, float acc) {
#if __has_builtin(__builtin_amdgcn_fdot2)
    return __builtin_amdgcn_fdot2(__builtin_bit_cast(hf2, a),
                                  __builtin_bit_cast(hf2, b), acc, false);
#else
    return acc + f16lo(a) * f16lo(b) + f16hi(a) * f16hi(b);
#endif
}

// ws: partials[5][NBLK] floats.
// k: 0=z_what_loss 1=z_pres_loss 2=pool_loss 3=objects_loss 4=n_obj
// launch_bounds arg2 acts as min-BLOCKS/CU on this toolchain (R3 evidence:
// arg2=4 -> 64-VGPR cap -> 12 MB spill). R7 A/B: arg2=3 -> 85-VGPR cap ->
// 3 blocks/CU residency (LDS 48.3 KB allows 3). R5/R7 showed arg2=2 kept
// residency at 2 blocks/CU (VGPR>85) and the LDS shrink alone gained 0.
__global__ __launch_bounds__(512, 3) void fused_losses(
    const float* __restrict__ z_what,
    const float* __restrict__ z_pres_prob,
    const float* __restrict__ z_pres,
    float* __restrict__ partials)
{
    __shared__ uint_t s_z [Nn * ZST];       // single z-slice tile (f16)          18432B
    __shared__ uint_t s_rm[Nn * ZST];       // row-max of e, f16 pairs            18432B
    __shared__ float  s_band[3 * Nn * 3];   // [di][cell][djslot] Gram band        9216B
    __shared__ float2 s_np[Nn];             // {p1, 1/max(n1,1e-5)}                2048B
    __shared__ float  s_red[8 * 5];

    const int tid  = threadIdx.x;      // 0..511
    const int cell = tid >> 1;         // 0..255
    const int half = tid & 1;          // which 16 dims
    const int lane = tid & 63;
    const int wv   = tid >> 6;         // wave 0..7
    const int b    = blockIdx.x;       // one block per batch element
    const int i = cell >> 4, j = cell & 15;
    const int hq = lane >> 4;          // k-chunk 0..3 for MFMA frags
    const int mq = lane & 15;          // row (A) / col (B) within tile

    // ---- per-cell presence probs for all 4 timesteps
    float p4[4];
    #pragma unroll
    for (int s = 0; s < 4; ++s)
        p4[s] = z_pres_prob[((size_t)s * Bn + b) * Nn + cell];
    float q4[4] = { 0.f, 0.f, 0.f, 0.f };
    if (half == 0) {
        #pragma unroll
        for (int s = 0; s < 4; ++s)
            q4[s] = z_pres[((size_t)s * Bn + b) * Nn + cell];
    }

    const float*  zbase = z_what + (((size_t)b) * Nn + cell) * Dn + half * 16;
    const size_t  ZSL   = (size_t)Bn * Nn * Dn;   // slice stride (floats)

    // ---- slice 0: f32 kept in zf, pack e, stage f16 tile 0 (Afr bootstrap)
    float zf[16];
    float n0sq;
    uint_t peC[8];
    {
        const float4* g = (const float4*)zbase;
        float ns = 0.f;
        uint_t* zp = &s_z[cell * ZST + half * 8];
        #pragma unroll
        for (int k2 = 0; k2 < 4; ++k2) {
            float4 v = g[k2];
            float c[4] = { v.x, v.y, v.z, v.w };
            #pragma unroll
            for (int cc = 0; cc < 4; ++cc) {
                ns += c[cc] * c[cc];
                zf[4 * k2 + cc] = c[cc];
            }
            u32x2 a; a.x = pkf16(c[0], c[1]); a.y = pkf16(c[2], c[3]);
            ((u32x2*)zp)[k2] = a;
            peC[2*k2]   = pkf16(fabsf(c[0]) * p4[0], fabsf(c[1]) * p4[0]);
            peC[2*k2+1] = pkf16(fabsf(c[2]) * p4[0], fabsf(c[3]) * p4[0]);
        }
        ns += __shfl_xor(ns, 1);
        n0sq = ns;
    }
    // prefetch slice 1
    float4 pf[4];
    {
        const float4* g = (const float4*)(zbase + ZSL);
        #pragma unroll
        for (int k2 = 0; k2 < 4; ++k2) pf[k2] = g[k2];
    }
    __syncthreads();   // P1: tile 0 visible

    // ---- bootstrap A-frags (rows I=2wv, 2wv+1 of slice 0); carried in regs after
    f16x8 Afr[2];
    #pragma unroll
    for (int ii = 0; ii < 2; ++ii) {
        const int I = 2 * wv + ii;
        const u32x2* ap = (const u32x2*)&s_z[(I * 16 + mq) * ZST + hq * 4];
        u32x2 a0 = ap[0], a1 = ap[1];
        u32x4 ta; ta.x = a0.x; ta.y = a0.y; ta.z = a1.x; ta.w = a1.y;
        Afr[ii] = __builtin_bit_cast(f16x8, ta);
    }
    __syncthreads();   // P2: Afr reads done before tile 1 overwrites s_z

    // ---- band-extraction constants (lane-dependent, loop-invariant)
    int  boff[4];
    bool bhit[4];
    #pragma unroll
    for (int r = 0; r < 4; ++r) {
        const int jr = 4 * hq + r;
        const int delta = (mq - jr) & 15;
        bhit[r] = (delta <= 1) || (delta == 15);
        const int slot = (delta == 15) ? 0 : (delta + 1);
        boff[r] = jr * 3 + slot;
    }

    float zwl_acc = 0.f, zpl_acc = 0.f, pool_acc = 0.f, obj_acc = 0.f, cnt = 0.f;

    #pragma unroll
    for (int t = 0; t < 3; ++t) {
        // ---- consume prefetched slice t+1; issue loads for slice t+2
        float4 ww[4] = { pf[0], pf[1], pf[2], pf[3] };
        if (t < 2) {
            const float4* g = (const float4*)(zbase + (size_t)(t + 2) * ZSL);
            #pragma unroll
            for (int k2 = 0; k2 < 4; ++k2) pf[k2] = g[k2];
        }
        const float p0 = p4[t], p1 = p4[t + 1];

        uint_t pzN[8], peN[8];
        float n1 = 0.f, zw = 0.f;
        #pragma unroll
        for (int k2 = 0; k2 < 4; ++k2) {
            float c[4] = { ww[k2].x, ww[k2].y, ww[k2].z, ww[k2].w };
            #pragma unroll
            for (int cc = 0; cc < 4; ++cc) {
                float d = c[cc] - zf[4 * k2 + cc];
                zw += d * d;
                n1 += c[cc] * c[cc];
                zf[4 * k2 + cc] = c[cc];
            }
            pzN[2*k2]   = pkf16(c[0], c[1]);
            pzN[2*k2+1] = pkf16(c[2], c[3]);
            peN[2*k2]   = pkf16(fabsf(c[0]) * p1, fabsf(c[1]) * p1);
            peN[2*k2+1] = pkf16(fabsf(c[2]) * p1, fabsf(c[3]) * p1);
        }
        zwl_acc += zw;
        n1 += __shfl_xor(n1, 1);
        const float n1sq = n1;
        const float inv_n0 = 1.0f / fmaxf(sqrtf(n0sq), 1e-5f);

        // ---- row-max of e (slice t) via in-wave shuffles (clamped edges)
        const int lL = (j > 0)  ? lane - 2 : lane;
        const int lR = (j < 15) ? lane + 2 : lane;
        uint_t rm[8];
        #pragma unroll
        for (int q = 0; q < 8; ++q) {
            uint_t e = peC[q];
            rm[q] = pkmax(e, pkmax(__shfl(e, lL), __shfl(e, lR)));
        }

        // ---- stage slice t+1 tile (over slice t), row-max, np
        {
            uint_t* zp = &s_z [cell * ZST + half * 8];
            uint_t* rp = &s_rm[cell * ZST + half * 8];
            #pragma unroll
            for (int q = 0; q < 4; ++q) {
                u32x2 a; a.x = pzN[2*q]; a.y = pzN[2*q+1];
                ((u32x2*)zp)[q] = a;
                u32x2 rr; rr.x = rm[2*q]; rr.y = rm[2*q+1];
                ((u32x2*)rp)[q] = rr;
            }
            if (half == 0)
                s_np[cell] = make_float2(p1, 1.0f / fmaxf(sqrtf(n1sq), 1e-5f));
        }
        __syncthreads();   // B1: tile + rm + np visible

        // ---- pool: col-max (clamped) + cosine vs |z1|*p1 (packed f16 dot)
        float dotp = 0.f, nasq = 0.f;
        {
            const int cu = (i > 0)  ? cell - Gn : cell;
            const int cd = (i < 15) ? cell + Gn : cell;
            const u32x2* ub = (const u32x2*)&s_rm[cu * ZST + half * 8];
            const u32x2* db = (const u32x2*)&s_rm[cd * ZST + half * 8];
            #pragma unroll
            for (int q = 0; q < 4; ++q) {
                u32x2 uu = ub[q], dd = db[q];
                #pragma unroll
                for (int c2 = 0; c2 < 2; ++c2) {
                    uint_t mx = pkmax(rm[2*q + c2], pkmax(uu[c2], dd[c2]));
                    uint_t za = pzN[2*q + c2] & 0x7FFF7FFFu;
                    dotp = dot2acc(mx, za, dotp);
                    nasq = dot2acc(mx, mx, nasq);
                }
            }
        }
        dotp += __shfl_xor(dotp, 1);
        nasq += __shfl_xor(nasq, 1);
        dotp *= p1;
        const float nbsq = n1sq * p1 * p1;    // exact ||(|z1|*p1)||^2
        float cosv = dotp / fmaxf(sqrtf(nasq) * sqrtf(nbsq), EPS_POOL);
        if (half == 0) pool_acc += -cosv * 0.5f * (p0 + p1);

        // ---- banded Gram via MFMA: A = slice t (regs, carried), B = slice t+1 (LDS)
        f16x8 Bfr[4];
        #pragma unroll
        for (int bx = 0; bx < 4; ++bx) {
            const int J = (2 * wv - 1 + bx) & 15;
            const u32x2* bp = (const u32x2*)&s_z[(J * 16 + mq) * ZST + hq * 4];
            u32x2 b0 = bp[0], b1 = bp[1];
            u32x4 tb; tb.x = b0.x; tb.y = b0.y; tb.z = b1.x; tb.w = b1.y;
            Bfr[bx] = __builtin_bit_cast(f16x8, tb);
        }
        #pragma unroll
        for (int di1 = 0; di1 < 3; ++di1) {
            #pragma unroll
            for (int ii = 0; ii < 2; ++ii) {
                const int I = 2 * wv + ii;
                f32x4 acc = { 0.f, 0.f, 0.f, 0.f };
                acc = __builtin_amdgcn_mfma_f32_16x16x32_f16(Afr[ii], Bfr[di1 + ii], acc, 0, 0, 0);
                const int base = (di1 * Nn + I * 16) * 3;
                #pragma unroll
                for (int r = 0; r < 4; ++r)
                    if (bhit[r]) s_band[base + boff[r]] = acc[r];
            }
        }
        // carry: this tile's J=2wv,2wv+1 frags are next iteration's A-frags
        Afr[0] = Bfr[1];
        Afr[1] = Bfr[2];
        __syncthreads();   // B2: band visible

        // ---- objects epilogue: 9 neighbors split 5/4 across the thread pair
        {
            float sum_sim = 0.f, max_sim = NEGBIG, anyf = 0.f;
            #pragma unroll
            for (int kk = 0; kk < 5; ++kk) {
                const int n = kk + 5 * half;   // half0: 0..4, half1: 5..9 (9 skipped)
                if (n < 9) {
                    const int di = (n >= 6) ? 1 : ((n >= 3) ? 0 : -1);
                    const int dj = n - (di + 1) * 3 - 1;
                    const int nb = (((i + di) & 15) << 4) | ((j + dj) & 15);
                    float2 np = s_np[nb];
                    float g = s_band[((di + 1) * Nn + cell) * 3 + (dj + 1)];
                    float s = g * inv_n0 * np.y;
                    bool m = np.x > THRESH_C;
                    sum_sim += m ? s : 0.f;
                    max_sim = fmaxf(max_sim, m ? s : NEGBIG);
                    anyf += m ? 1.f : 0.f;
                }
            }
            sum_sim += __shfl_xor(sum_sim, 1);
            anyf    += __shfl_xor(anyf, 1);
            max_sim  = fmaxf(max_sim, __shfl_xor(max_sim, 1));
            const bool det = p0 > THRESH_C;
            if (det && half == 0) {
                cnt += 1.f;
                if (anyf > 0.f) obj_acc += sum_sim - ZCMW * max_sim;
            }
        }

        // ---- z_pres_loss term for this transition (t < T-2)
        if (half == 0 && t < 2) {
            const float qa = q4[t], qb = q4[t + 1], qc = q4[t + 2];
            const float sim = 1.f - (qc - qa) * (qc - qa);
            zpl_acc += sim * ((qc - qb) * (qc - qb) + (qa - qb) * (qa - qb));
        }

        if (t < 2) __syncthreads();   // B3: epilogue/np reads done before next stage

        // ---- roll state
        n0sq = n1sq;
        #pragma unroll
        for (int q = 0; q < 8; ++q) peC[q] = peN[q];
    }

    // ---- block reduction: wave shuffle -> LDS -> partials write. No atomics,
    // no fences, no single-kernel fan-in tail (R4: tail was ~30 us of 45 us).
    float vals[5] = { zwl_acc, zpl_acc, pool_acc, obj_acc, cnt };
    #pragma unroll
    for (int k = 0; k < 5; ++k) {
        float v = vals[k];
        #pragma unroll
        for (int off = 32; off; off >>= 1) v += __shfl_down(v, off);
        if (lane == 0) s_red[wv * 5 + k] = v;
    }
    __syncthreads();

    if (tid == 0) {
        #pragma unroll
        for (int k = 0; k < 5; ++k) {
            float v = 0.f;
            #pragma unroll
            for (int w = 0; w < 8; ++w) v += s_red[w * 5 + k];
            partials[k * NBLK + blockIdx.x] = v;
        }
    }
}

// 1 block, 512 threads (= NBLK): deterministic final reduction + output.
__global__ __launch_bounds__(512, 1) void finalize(
    const float* __restrict__ partials,
    const float* __restrict__ base_losses,
    const int* __restrict__ gstep,
    float* __restrict__ out)
{
    __shared__ float s_red[8 * 5];
    const int tid  = threadIdx.x;
    const int lane = tid & 63;
    const int wv   = tid >> 6;

    float acc[5];
    #pragma unroll
    for (int k = 0; k < 5; ++k) acc[k] = partials[k * NBLK + tid];

    #pragma unroll
    for (int k = 0; k < 5; ++k) {
        float v = acc[k];
        #pragma unroll
        for (int off = 32; off; off >>= 1) v += __shfl_down(v, off);
        if (lane == 0) s_red[wv * 5 + k] = v;
    }
    __syncthreads();

    if (tid == 0) {
        float r[5];
        #pragma unroll
        for (int k = 0; k < 5; ++k) {
            float v = 0.f;
            #pragma unroll
            for (int w = 0; w < 8; ++w) v += s_red[w * 5 + k];
            r[k] = v;
        }
        float bl = base_losses[0] + base_losses[1] + base_losses[2] + base_losses[3];
        float scaling = fminf(1.0f, (float)gstep[0] / 300000.0f);
        out[0] = bl + r[0] * 10.0f + r[1] + r[2] + r[3] * scaling * 10.0f;
        out[1] = r[0];
        out[2] = r[1];
        out[3] = r[2];
        out[4] = r[3];
        out[5] = r[4];
    }
}

extern "C" void kernel_launch(void* const* d_in, const int* in_sizes, int n_in,
                              void* d_out, int out_size, void* d_ws, size_t ws_size,
                              hipStream_t stream) {
    const float* z_what      = (const float*)d_in[0];
    const float* z_pres_prob = (const float*)d_in[1];
    const float* z_pres      = (const float*)d_in[2];
    const float* base_losses = (const float*)d_in[3];
    const int*   gstep       = (const int*)d_in[4];

    float* partials = (float*)d_ws;   // 5*NBLK floats

    fused_losses<<<dim3(NBLK), dim3(512), 0, stream>>>(
        z_what, z_pres_prob, z_pres, partials);
    finalize<<<dim3(1), dim3(512), 0, stream>>>(
        partials, base_losses, gstep, (float*)d_out);
}

// Round 9
// 114.131 us; speedup vs baseline: 1.4003x; 1.0052x over previous
//
#include <hip/hip_runtime.h>

// Problem constants (match reference)
#define Tn 4
#define Bn 512
#define Gn 16
#define Nn 256               // Gn*Gn
#define Dn 32
#define NBLK Bn              // 512 blocks, one per batch element b
#define ZST 18               // uint stride/cell in f16 tiles (72B, b64-aligned)

#define THRESH_C 0.5f
#define EPS_POOL 1e-6f
#define ZCMW 5.0f
#define NEGBIG -1e30f

typedef unsigned int uint_t;
typedef __attribute__((ext_vector_type(2))) unsigned short u16x2;
typedef __attribute__((ext_vector_type(2))) unsigned int   u32x2;
typedef __attribute__((ext_vector_type(4))) unsigned int   u32x4;
typedef __attribute__((ext_vector_type(8))) _Float16       f16x8;
typedef __attribute__((ext_vector_type(2))) __fp16         hf2;
typedef __attribute__((ext_vector_type(4))) float          f32x4;

static_assert(sizeof(f16x8) == 16, "f16x8 must be 16B");

// pack two f32 -> two f16 (RTZ; monotone on non-negatives: commutes with max)
__device__ __forceinline__ uint_t pkf16(float lo, float hi) {
    auto h = __builtin_amdgcn_cvt_pkrtz(lo, hi);   // __fp16 ext_vector_type(2)
    return __builtin_bit_cast(uint_t, h);
}
__device__ __forceinline__ float f16lo(uint_t u) {
    return (float)__builtin_bit_cast(_Float16, (unsigned short)(u & 0xFFFFu));
}
__device__ __forceinline__ float f16hi(uint_t u) {
    return (float)__builtin_bit_cast(_Float16, (unsigned short)(u >> 16));
}
// packed max of two f16 pairs; valid because all values >= 0 (f16 order == u16 order)
__device__ __forceinline__ uint_t pkmax(uint_t a, uint_t b) {
    u16x2 r = __builtin_elementwise_max(__builtin_bit_cast(u16x2, a),
                                        __builtin_bit_cast(u16x2, b));
    return __builtin_bit_cast(uint_t, r);
}
// acc += a.lo*b.lo + a.hi*b.hi  (f16 inputs, f32 accumulate)
__device__ __forceinline__ float dot2acc(uint_t a, uint_t b, float acc) {
#if __has_builtin(__builtin_amdgcn_fdot2)
    return __builtin_amdgcn_fdot2(__builtin_bit_cast(hf2, a),
                                  __builtin_bit_cast(hf2, b), acc, false);
#else
    return acc + f16lo(a) * f16lo(b) + f16hi(a) * f16hi(b);
#endif
}

// ws: partials[5][NBLK] floats.
// k: 0=z_what_loss 1=z_pres_loss 2=pool_loss 3=objects_loss 4=n_obj
// launch_bounds arg2 acts as min-BLOCKS/CU on this toolchain (R3 evidence:
// arg2=4 -> 64-VGPR cap -> 12 MB spill; R8: arg2=3 -> 85-VGPR cap, -2us).
// R8 note: 512 blocks = exactly 2 blocks/CU; arg2=3's gain was codegen, not
// residency. Barrier structure: B2 removed (band is wave-local — wave wv
// writes band rows I=2wv,2wv+1 = its own cells 32wv..32wv+31; same-wave LDS
// ops are program-ordered). B1 protects cross-wave stage->read; B3 protects
// read->next-stage overwrite.
__global__ __launch_bounds__(512, 3) void fused_losses(
    const float* __restrict__ z_what,
    const float* __restrict__ z_pres_prob,
    const float* __restrict__ z_pres,
    float* __restrict__ partials)
{
    __shared__ uint_t s_z [Nn * ZST];       // single z-slice tile (f16)          18432B
    __shared__ uint_t s_rm[Nn * ZST];       // row-max of e, f16 pairs            18432B
    __shared__ float  s_band[3 * Nn * 3];   // [di][cell][djslot] Gram band        9216B
    __shared__ float2 s_np[Nn];             // {p1, 1/max(n1,1e-5)}                2048B
    __shared__ float  s_red[8 * 5];

    const int tid  = threadIdx.x;      // 0..511
    const int cell = tid >> 1;         // 0..255
    const int half = tid & 1;          // which 16 dims
    const int lane = tid & 63;
    const int wv   = tid >> 6;         // wave 0..7
    const int b    = blockIdx.x;       // one block per batch element
    const int i = cell >> 4, j = cell & 15;
    const int hq = lane >> 4;          // k-chunk 0..3 for MFMA frags
    const int mq = lane & 15;          // row (A) / col (B) within tile

    // ---- per-cell presence probs for all 4 timesteps
    float p4[4];
    #pragma unroll
    for (int s = 0; s < 4; ++s)
        p4[s] = z_pres_prob[((size_t)s * Bn + b) * Nn + cell];
    float q4[4] = { 0.f, 0.f, 0.f, 0.f };
    if (half == 0) {
        #pragma unroll
        for (int s = 0; s < 4; ++s)
            q4[s] = z_pres[((size_t)s * Bn + b) * Nn + cell];
    }

    const float*  zbase = z_what + (((size_t)b) * Nn + cell) * Dn + half * 16;
    const size_t  ZSL   = (size_t)Bn * Nn * Dn;   // slice stride (floats)

    // ---- slice 0: f32 kept in zf, pack e, stage f16 tile 0 (Afr bootstrap)
    float zf[16];
    float n0sq;
    uint_t peC[8];
    {
        const float4* g = (const float4*)zbase;
        float ns = 0.f;
        uint_t* zp = &s_z[cell * ZST + half * 8];
        #pragma unroll
        for (int k2 = 0; k2 < 4; ++k2) {
            float4 v = g[k2];
            float c[4] = { v.x, v.y, v.z, v.w };
            #pragma unroll
            for (int cc = 0; cc < 4; ++cc) {
                ns += c[cc] * c[cc];
                zf[4 * k2 + cc] = c[cc];
            }
            u32x2 a; a.x = pkf16(c[0], c[1]); a.y = pkf16(c[2], c[3]);
            ((u32x2*)zp)[k2] = a;
            peC[2*k2]   = pkf16(fabsf(c[0]) * p4[0], fabsf(c[1]) * p4[0]);
            peC[2*k2+1] = pkf16(fabsf(c[2]) * p4[0], fabsf(c[3]) * p4[0]);
        }
        ns += __shfl_xor(ns, 1);
        n0sq = ns;
    }
    // prefetch slice 1
    float4 pf[4];
    {
        const float4* g = (const float4*)(zbase + ZSL);
        #pragma unroll
        for (int k2 = 0; k2 < 4; ++k2) pf[k2] = g[k2];
    }
    __syncthreads();   // P1: tile 0 visible

    // ---- bootstrap A-frags (rows I=2wv, 2wv+1 of slice 0); carried in regs after
    f16x8 Afr[2];
    #pragma unroll
    for (int ii = 0; ii < 2; ++ii) {
        const int I = 2 * wv + ii;
        const u32x2* ap = (const u32x2*)&s_z[(I * 16 + mq) * ZST + hq * 4];
        u32x2 a0 = ap[0], a1 = ap[1];
        u32x4 ta; ta.x = a0.x; ta.y = a0.y; ta.z = a1.x; ta.w = a1.y;
        Afr[ii] = __builtin_bit_cast(f16x8, ta);
    }
    __syncthreads();   // P2: Afr reads done before tile 1 overwrites s_z

    // ---- band-extraction constants (lane-dependent, loop-invariant)
    int  boff[4];
    bool bhit[4];
    #pragma unroll
    for (int r = 0; r < 4; ++r) {
        const int jr = 4 * hq + r;
        const int delta = (mq - jr) & 15;
        bhit[r] = (delta <= 1) || (delta == 15);
        const int slot = (delta == 15) ? 0 : (delta + 1);
        boff[r] = jr * 3 + slot;
    }

    float zwl_acc = 0.f, zpl_acc = 0.f, pool_acc = 0.f, obj_acc = 0.f, cnt = 0.f;

    #pragma unroll
    for (int t = 0; t < 3; ++t) {
        // ---- consume prefetched slice t+1; issue loads for slice t+2
        float4 ww[4] = { pf[0], pf[1], pf[2], pf[3] };
        if (t < 2) {
            const float4* g = (const float4*)(zbase + (size_t)(t + 2) * ZSL);
            #pragma unroll
            for (int k2 = 0; k2 < 4; ++k2) pf[k2] = g[k2];
        }
        const float p0 = p4[t], p1 = p4[t + 1];

        uint_t pzN[8], peN[8];
        float n1 = 0.f, zw = 0.f;
        #pragma unroll
        for (int k2 = 0; k2 < 4; ++k2) {
            float c[4] = { ww[k2].x, ww[k2].y, ww[k2].z, ww[k2].w };
            #pragma unroll
            for (int cc = 0; cc < 4; ++cc) {
                float d = c[cc] - zf[4 * k2 + cc];
                zw += d * d;
                n1 += c[cc] * c[cc];
                zf[4 * k2 + cc] = c[cc];
            }
            pzN[2*k2]   = pkf16(c[0], c[1]);
            pzN[2*k2+1] = pkf16(c[2], c[3]);
            peN[2*k2]   = pkf16(fabsf(c[0]) * p1, fabsf(c[1]) * p1);
            peN[2*k2+1] = pkf16(fabsf(c[2]) * p1, fabsf(c[3]) * p1);
        }
        zwl_acc += zw;
        n1 += __shfl_xor(n1, 1);
        const float n1sq = n1;
        const float inv_n0 = 1.0f / fmaxf(sqrtf(n0sq), 1e-5f);

        // ---- row-max of e (slice t) via in-wave shuffles (clamped edges)
        const int lL = (j > 0)  ? lane - 2 : lane;
        const int lR = (j < 15) ? lane + 2 : lane;
        uint_t rm[8];
        #pragma unroll
        for (int q = 0; q < 8; ++q) {
            uint_t e = peC[q];
            rm[q] = pkmax(e, pkmax(__shfl(e, lL), __shfl(e, lR)));
        }

        // ---- stage slice t+1 tile (over slice t), row-max, np
        {
            uint_t* zp = &s_z [cell * ZST + half * 8];
            uint_t* rp = &s_rm[cell * ZST + half * 8];
            #pragma unroll
            for (int q = 0; q < 4; ++q) {
                u32x2 a; a.x = pzN[2*q]; a.y = pzN[2*q+1];
                ((u32x2*)zp)[q] = a;
                u32x2 rr; rr.x = rm[2*q]; rr.y = rm[2*q+1];
                ((u32x2*)rp)[q] = rr;
            }
            if (half == 0)
                s_np[cell] = make_float2(p1, 1.0f / fmaxf(sqrtf(n1sq), 1e-5f));
        }
        __syncthreads();   // B1: tile + rm + np visible

        // ---- pool: col-max (clamped) + cosine vs |z1|*p1 (packed f16 dot)
        float dotp = 0.f, nasq = 0.f;
        {
            const int cu = (i > 0)  ? cell - Gn : cell;
            const int cd = (i < 15) ? cell + Gn : cell;
            const u32x2* ub = (const u32x2*)&s_rm[cu * ZST + half * 8];
            const u32x2* db = (const u32x2*)&s_rm[cd * ZST + half * 8];
            #pragma unroll
            for (int q = 0; q < 4; ++q) {
                u32x2 uu = ub[q], dd = db[q];
                #pragma unroll
                for (int c2 = 0; c2 < 2; ++c2) {
                    uint_t mx = pkmax(rm[2*q + c2], pkmax(uu[c2], dd[c2]));
                    uint_t za = pzN[2*q + c2] & 0x7FFF7FFFu;
                    dotp = dot2acc(mx, za, dotp);
                    nasq = dot2acc(mx, mx, nasq);
                }
            }
        }
        dotp += __shfl_xor(dotp, 1);
        nasq += __shfl_xor(nasq, 1);
        dotp *= p1;
        const float nbsq = n1sq * p1 * p1;    // exact ||(|z1|*p1)||^2
        float cosv = dotp / fmaxf(sqrtf(nasq) * sqrtf(nbsq), EPS_POOL);
        if (half == 0) pool_acc += -cosv * 0.5f * (p0 + p1);

        // ---- banded Gram via MFMA: A = slice t (regs, carried), B = slice t+1 (LDS)
        f16x8 Bfr[4];
        #pragma unroll
        for (int bx = 0; bx < 4; ++bx) {
            const int J = (2 * wv - 1 + bx) & 15;
            const u32x2* bp = (const u32x2*)&s_z[(J * 16 + mq) * ZST + hq * 4];
            u32x2 b0 = bp[0], b1 = bp[1];
            u32x4 tb; tb.x = b0.x; tb.y = b0.y; tb.z = b1.x; tb.w = b1.y;
            Bfr[bx] = __builtin_bit_cast(f16x8, tb);
        }
        #pragma unroll
        for (int di1 = 0; di1 < 3; ++di1) {
            #pragma unroll
            for (int ii = 0; ii < 2; ++ii) {
                const int I = 2 * wv + ii;
                f32x4 acc = { 0.f, 0.f, 0.f, 0.f };
                acc = __builtin_amdgcn_mfma_f32_16x16x32_f16(Afr[ii], Bfr[di1 + ii], acc, 0, 0, 0);
                const int base = (di1 * Nn + I * 16) * 3;
                #pragma unroll
                for (int r = 0; r < 4; ++r)
                    if (bhit[r]) s_band[base + boff[r]] = acc[r];
            }
        }
        // carry: this tile's J=2wv,2wv+1 frags are next iteration's A-frags
        Afr[0] = Bfr[1];
        Afr[1] = Bfr[2];
        // NO barrier here (was B2): band rows read below are this wave's own
        // writes (wave-local LDS, program-ordered within a wave).

        // ---- objects epilogue: 9 neighbors split 5/4 across the thread pair
        {
            float sum_sim = 0.f, max_sim = NEGBIG, anyf = 0.f;
            #pragma unroll
            for (int kk = 0; kk < 5; ++kk) {
                const int n = kk + 5 * half;   // half0: 0..4, half1: 5..9 (9 skipped)
                if (n < 9) {
                    const int di = (n >= 6) ? 1 : ((n >= 3) ? 0 : -1);
                    const int dj = n - (di + 1) * 3 - 1;
                    const int nb = (((i + di) & 15) << 4) | ((j + dj) & 15);
                    float2 np = s_np[nb];
                    float g = s_band[((di + 1) * Nn + cell) * 3 + (dj + 1)];
                    float s = g * inv_n0 * np.y;
                    bool m = np.x > THRESH_C;
                    sum_sim += m ? s : 0.f;
                    max_sim = fmaxf(max_sim, m ? s : NEGBIG);
                    anyf += m ? 1.f : 0.f;
                }
            }
            sum_sim += __shfl_xor(sum_sim, 1);
            anyf    += __shfl_xor(anyf, 1);
            max_sim  = fmaxf(max_sim, __shfl_xor(max_sim, 1));
            const bool det = p0 > THRESH_C;
            if (det && half == 0) {
                cnt += 1.f;
                if (anyf > 0.f) obj_acc += sum_sim - ZCMW * max_sim;
            }
        }

        // ---- z_pres_loss term for this transition (t < T-2)
        if (half == 0 && t < 2) {
            const float qa = q4[t], qb = q4[t + 1], qc = q4[t + 2];
            const float sim = 1.f - (qc - qa) * (qc - qa);
            zpl_acc += sim * ((qc - qb) * (qc - qb) + (qa - qb) * (qa - qb));
        }

        if (t < 2) __syncthreads();   // B3: all reads done before next stage writes

        // ---- roll state
        n0sq = n1sq;
        #pragma unroll
        for (int q = 0; q < 8; ++q) peC[q] = peN[q];
    }

    // ---- block reduction: wave shuffle -> LDS -> partials write. No atomics,
    // no fences, no single-kernel fan-in tail (R4: tail was ~30 us of 45 us).
    float vals[5] = { zwl_acc, zpl_acc, pool_acc, obj_acc, cnt };
    #pragma unroll
    for (int k = 0; k < 5; ++k) {
        float v = vals[k];
        #pragma unroll
        for (int off = 32; off; off >>= 1) v += __shfl_down(v, off);
        if (lane == 0) s_red[wv * 5 + k] = v;
    }
    __syncthreads();

    if (tid == 0) {
        #pragma unroll
        for (int k = 0; k < 5; ++k) {
            float v = 0.f;
            #pragma unroll
            for (int w = 0; w < 8; ++w) v += s_red[w * 5 + k];
            partials[k * NBLK + blockIdx.x] = v;
        }
    }
}

// 1 block, 512 threads (= NBLK): deterministic final reduction + output.
__global__ __launch_bounds__(512, 1) void finalize(
    const float* __restrict__ partials,
    const float* __restrict__ base_losses,
    const int* __restrict__ gstep,
    float* __restrict__ out)
{
    __shared__ float s_red[8 * 5];
    const int tid  = threadIdx.x;
    const int lane = tid & 63;
    const int wv   = tid >> 6;

    float acc[5];
    #pragma unroll
    for (int k = 0; k < 5; ++k) acc[k] = partials[k * NBLK + tid];

    #pragma unroll
    for (int k = 0; k < 5; ++k) {
        float v = acc[k];
        #pragma unroll
        for (int off = 32; off; off >>= 1) v += __shfl_down(v, off);
        if (lane == 0) s_red[wv * 5 + k] = v;
    }
    __syncthreads();

    if (tid == 0) {
        float r[5];
        #pragma unroll
        for (int k = 0; k < 5; ++k) {
            float v = 0.f;
            #pragma unroll
            for (int w = 0; w < 8; ++w) v += s_red[w * 5 + k];
            r[k] = v;
        }
        float bl = base_losses[0] + base_losses[1] + base_losses[2] + base_losses[3];
        float scaling = fminf(1.0f, (float)gstep[0] / 300000.0f);
        out[0] = bl + r[0] * 10.0f + r[1] + r[2] + r[3] * scaling * 10.0f;
        out[1] = r[0];
        out[2] = r[1];
        out[3] = r[2];
        out[4] = r[3];
        out[5] = r[4];
    }
}

extern "C" void kernel_launch(void* const* d_in, const int* in_sizes, int n_in,
                              void* d_out, int out_size, void* d_ws, size_t ws_size,
                              hipStream_t stream) {
    const float* z_what      = (const float*)d_in[0];
    const float* z_pres_prob = (const float*)d_in[1];
    const float* z_pres      = (const float*)d_in[2];
    const float* base_losses = (const float*)d_in[3];
    const int*   gstep       = (const int*)d_in[4];

    float* partials = (float*)d_ws;   // 5*NBLK floats

    fused_losses<<<dim3(NBLK), dim3(512), 0, stream>>>(
        z_what, z_pres_prob, z_pres, partials);
    finalize<<<dim3(1), dim3(512), 0, stream>>>(
        partials, base_losses, gstep, (float*)d_out);
}